// Round 14
// baseline (310.183 us; speedup 1.0000x reference)
//
#include <hip/hip_runtime.h>
#include <math.h>

#define NPAPER 100000
#define NAUTH  50000
#define DIM    128
#define NEDGE  500000
#define NCLS   16
#define NTOT   (2*NPAPER + NAUTH)   // concatenated CSR node space (C | W | R)
#define NB     245                  // buckets of 1024 nodes over NTOT
#define CHUNK_A 11776               // edges per bucketize block
#define NBLK_A  128                 // ceil(3*NEDGE / CHUNK_A)
#define PBLK2  ((NPAPER + 255) / 256)   // 391 (256-row GEMM tiles)
#define ABLK2  ((NAUTH  + 255) / 256)   // 196

typedef unsigned int   uint;
typedef unsigned short ushort;
typedef unsigned char  uchar;
using short8 = __attribute__((ext_vector_type(8))) short;
using f32x4  = __attribute__((ext_vector_type(4))) float;

__device__ __forceinline__ float b2f(uint u) {
    return __uint_as_float(u << 16);
}
__device__ __forceinline__ ushort f2b(float f) {   // round-to-nearest-even
    uint x = __float_as_uint(f);
    return (ushort)((x + 0x7fffu + ((x >> 16) & 1u)) >> 16);
}

// global_load_lds: linear LDS dest (wave base + lane*16), per-lane global src.
#define GLD_LDS16(srcp, ldsp) \
    __builtin_amdgcn_global_load_lds( \
        (const __attribute__((address_space(1))) void*)(srcp), \
        (__attribute__((address_space(3))) void*)(ldsp), 16, 0, 0)

// ---------------------------------------------------------------------------
// prep bodies (block-indexed device functions, merged into lean misc kernels)
// ---------------------------------------------------------------------------
__device__ __forceinline__ void prep_weights_body(int b, int tid,
    const float* __restrict__ Wl, const float* __restrict__ Wr,
    const float* __restrict__ bl,
    float* __restrict__ Bp, float* __restrict__ Ba,
    float* __restrict__ biasp, float* __restrict__ biasa)
{
    int t = b * 256 + tid;
    if (t < 2*384*128) {
        int l = t / (384*128); int rem = t - l*(384*128);
        int k = rem >> 7, j = rem & 127;
        float v;
        if (k < 128)      v = Wl[((l*3+0)*128 + j)*128 + k];
        else if (k < 256) v = Wl[((l*3+1)*128 + j)*128 + (k-128)];
        else              v = Wr[((l*3+0)*128 + j)*128 + (k-256)]
                            + Wr[((l*3+1)*128 + j)*128 + (k-256)];
        Bp[t] = v;
        return;
    }
    t -= 2*384*128;
    if (t < 2*256*128) {
        int l = t / (256*128); int rem = t - l*(256*128);
        int k = rem >> 7, j = rem & 127;
        Ba[t] = (k < 128) ? Wl[((l*3+2)*128 + j)*128 + k]
                          : Wr[((l*3+2)*128 + j)*128 + (k-128)];
        return;
    }
    t -= 2*256*128;
    if (t < 256) { int l=t>>7, j=t&127; biasp[t] = bl[(l*3+0)*128+j] + bl[(l*3+1)*128+j]; return; }
    t -= 256;
    if (t < 256) { int l=t>>7, j=t&127; biasa[t] = bl[(l*3+2)*128+j]; return; }
}

// residual fold + bf16 + PACK into MFMA-fragment order.
__device__ __forceinline__ size_t pack_off(int j, int k) {
    int kstep = k >> 6, ks = (k >> 5) & 1, g4 = (k >> 3) & 3, jj = k & 7;
    int f = j >> 4, l15 = j & 15;
    return (size_t)kstep*8192 + (size_t)(ks*512 + f*64 + g4*16 + l15)*8 + jj;
}

__device__ __forceinline__ void build_bt_body(int b, int tid,
    const float* __restrict__ Bp, const float* __restrict__ Ba,
    const float* __restrict__ linp, const float* __restrict__ lina,
    ushort* __restrict__ Btp, ushort* __restrict__ Bta)
{
    int t = b * 256 + tid;
    if (t < 2*128*384) {
        int l = t / (128*384); int rem = t - l*(128*384);
        int j = rem / 384, k = rem - j*384;
        const float* brow = Bp + (size_t)l*384*128 + (size_t)k*128;
        float v = brow[j];
        if (l == 0) {
            const float* lrow = linp + (size_t)j*128;
            float s = 0.f;
            #pragma unroll 8
            for (int m = 0; m < 128; m++) s += brow[m] * lrow[m];
            v += s;
        }
        Btp[(size_t)l*49152 + pack_off(j, k)] = f2b(v);
        return;
    }
    t -= 2*128*384;
    if (t < 2*128*256) {
        int l = t / (128*256); int rem = t - l*(128*256);
        int j = rem / 256, k = rem - j*256;
        const float* brow = Ba + (size_t)l*256*128 + (size_t)k*128;
        float v = brow[j];
        if (l == 0) {
            const float* lrow = lina + (size_t)j*128;
            float s = 0.f;
            #pragma unroll 8
            for (int m = 0; m < 128; m++) s += brow[m] * lrow[m];
            v += s;
        }
        Bta[(size_t)l*32768 + pack_off(j, k)] = f2b(v);
    }
}

__device__ __forceinline__ void fold_bias_body(int b, int tid,
    const float* __restrict__ biasp, const float* __restrict__ biasa,
    const float* __restrict__ linp, const float* __restrict__ lina,
    float* __restrict__ biasp2, float* __restrict__ biasa2)
{
    int t = b * 256 + tid;   // 512 total
    int isa = t >> 8; int r = t & 255;
    int l = r >> 7, j = r & 127;
    const float* bsrc = isa ? biasa : biasp;
    const float* lin  = isa ? lina  : linp;
    float v = bsrc[r];
    if (l == 0) {
        float s = 0.f;
        for (int k = 0; k < 128; k++) s += bsrc[k] * lin[j*128 + k];
        v += s;
    }
    (isa ? biasa2 : biasp2)[r] = v;
}

__device__ __forceinline__ void to_bf16_body(int b, int tid,
    const float* __restrict__ xp, const float* __restrict__ xa,
    ushort* __restrict__ yp, ushort* __restrict__ ya)
{
    int i = b * 256 + tid;
    const int n4p = NPAPER * DIM / 4;
    const float* x; ushort* y;
    if (i < n4p) { x = xp; y = yp; }
    else { x = xa; y = ya; i -= n4p; }
    float4 v = ((const float4*)x)[i];
    uint2 o;
    o.x = (uint)f2b(v.x) | ((uint)f2b(v.y) << 16);
    o.y = (uint)f2b(v.z) | ((uint)f2b(v.w) << 16);
    ((uint2*)y)[i] = o;
}

// ---------------------------------------------------------------------------
__device__ __forceinline__ int edge_g(const int* __restrict__ eiC,
                                      const int* __restrict__ eiW,
                                      const int* __restrict__ eiR, int i)
{
    int tpe = (i >= 2*NEDGE) ? 2 : ((i >= NEDGE) ? 1 : 0);
    int e = i - tpe*NEDGE;
    const int* ei = (tpe == 0) ? eiC : ((tpe == 1) ? eiW : eiR);
    int base = (tpe == 0) ? 0 : ((tpe == 1) ? NPAPER : 2*NPAPER);
    return base + ei[NEDGE + e];
}

// misc0: [bucket_count (128) | prep_weights (642) | to_bf16 (18750)]
#define PREPB 642
__global__ __launch_bounds__(256) void misc0(
    const int* __restrict__ eiC, const int* __restrict__ eiW,
    const int* __restrict__ eiR, int* __restrict__ bucketCount,
    const float* __restrict__ Wl, const float* __restrict__ Wr,
    const float* __restrict__ bl,
    float* __restrict__ Bp, float* __restrict__ Ba,
    float* __restrict__ biasp, float* __restrict__ biasa,
    const float* __restrict__ xpf, const float* __restrict__ xaf,
    ushort* __restrict__ xpb, ushort* __restrict__ xab)
{
    __shared__ int h[256];
    int b = blockIdx.x, t = threadIdx.x;
    if (b < NBLK_A) {
        h[t] = 0;
        __syncthreads();
        int start = b * CHUNK_A;
        int n = 3*NEDGE - start; if (n > CHUNK_A) n = CHUNK_A;
        for (int i = t; i < n; i += 256)
            atomicAdd(&h[edge_g(eiC, eiW, eiR, start + i) >> 10], 1);
        __syncthreads();
        if (h[t]) atomicAdd(&bucketCount[t], h[t]);
        return;
    }
    b -= NBLK_A;
    if (b < PREPB) {
        prep_weights_body(b, t, Wl, Wr, bl, Bp, Ba, biasp, biasa);
        return;
    }
    b -= PREPB;
    to_bf16_body(b, t, xpf, xaf, xpb, xab);
}

// misc1: [fold_bias (2) | build_bt (640) | bucket_emit (128)]
#define BTB 640
__global__ __launch_bounds__(256) void misc1(
    const float* __restrict__ biasp, const float* __restrict__ biasa,
    const float* __restrict__ linp, const float* __restrict__ lina,
    float* __restrict__ biasp2, float* __restrict__ biasa2,
    const float* __restrict__ Bp, const float* __restrict__ Ba,
    ushort* __restrict__ Btp, ushort* __restrict__ Bta,
    const int* __restrict__ eiC, const int* __restrict__ eiW,
    const int* __restrict__ eiR,
    const int* __restrict__ bucketCount, int* __restrict__ emitCursor,
    uint2* __restrict__ stage)
{
    int blk = blockIdx.x, t = threadIdx.x;
    if (blk < 2) {
        fold_bias_body(blk, t, biasp, biasa, linp, lina, biasp2, biasa2);
        return;
    }
    blk -= 2;
    if (blk < BTB) {
        build_bt_body(blk, t, Bp, Ba, linp, lina, Btp, Bta);
        return;
    }
    int b = blk - BTB;

    __shared__ uchar  bId [CHUNK_A];
    __shared__ ushort rnk [CHUNK_A];
    __shared__ ushort perm[CHUNK_A];
    __shared__ uchar  posB[CHUNK_A];
    __shared__ int lcnt[256];
    __shared__ int lpre[256];
    __shared__ int bbase[256];
    __shared__ int bbs[256];

    // redundant exclusive scan of bucketCount -> bucket bases
    {
        int v = (t < NB) ? bucketCount[t] : 0;
        bbs[t] = v;
        __syncthreads();
        for (int o = 1; o < 256; o <<= 1) {
            int x = (t >= o) ? bbs[t - o] : 0;
            __syncthreads();
            bbs[t] += x;
            __syncthreads();
        }
        int inc = bbs[t];
        __syncthreads();
        bbs[t] = inc - ((t < NB) ? bucketCount[t] : 0);   // exclusive
        __syncthreads();
    }

    int start = b * CHUNK_A;
    int n = 3*NEDGE - start; if (n > CHUNK_A) n = CHUNK_A;
    lcnt[t] = 0;
    __syncthreads();
    for (int i = t; i < n; i += 256) {
        int bb = edge_g(eiC, eiW, eiR, start + i) >> 10;
        bId[i] = (uchar)bb;
        rnk[i] = (ushort)atomicAdd(&lcnt[bb], 1);
    }
    __syncthreads();
    lpre[t] = lcnt[t];
    __syncthreads();
    for (int o = 1; o < 256; o <<= 1) {
        int x = (t >= o) ? lpre[t - o] : 0;
        __syncthreads();
        lpre[t] += x;
        __syncthreads();
    }
    if (lcnt[t] > 0) bbase[t] = bbs[t] + atomicAdd(&emitCursor[t], lcnt[t]);
    __syncthreads();
    for (int i = t; i < n; i += 256) {
        int bb = bId[i];
        int p = (lpre[bb] - lcnt[bb]) + rnk[i];
        perm[p] = (ushort)i;
        posB[p] = (uchar)bb;
    }
    __syncthreads();
    for (int p = t; p < n; p += 256) {
        int bb = posB[p];
        int i = start + perm[p];
        int tpe = (i >= 2*NEDGE) ? 2 : ((i >= NEDGE) ? 1 : 0);
        int e = i - tpe*NEDGE;
        const int* ei = (tpe == 0) ? eiC : ((tpe == 1) ? eiW : eiR);
        int base = (tpe == 0) ? 0 : ((tpe == 1) ? NPAPER : 2*NPAPER);
        uint2 o2;
        o2.x = (uint)(base + ei[NEDGE + e]);
        o2.y = (uint)ei[e];
        stage[bbase[bb] + (p - (lpre[bb] - lcnt[bb]))] = o2;
    }
}

// Per-bucket CSR finalize; bucket bases scanned inline from bucketCount.
__global__ __launch_bounds__(256) void csr_fillB(
    const uint2* __restrict__ stage, const int* __restrict__ bucketCount,
    int* __restrict__ rowAll, int* __restrict__ colAll)
{
    __shared__ int cnt[1024];
    __shared__ int part[256];
    __shared__ int bbs[256];
    int b = blockIdx.x;
    int t = threadIdx.x;

    // inline exclusive scan of bucketCount
    {
        int v = (t < NB) ? bucketCount[t] : 0;
        bbs[t] = v;
        __syncthreads();
        for (int o = 1; o < 256; o <<= 1) {
            int x = (t >= o) ? bbs[t - o] : 0;
            __syncthreads();
            bbs[t] += x;
            __syncthreads();
        }
        int inc = bbs[t];
        __syncthreads();
        bbs[t] = inc - ((t < NB) ? bucketCount[t] : 0);
        __syncthreads();
    }
    int g0 = b << 10;
    int nn = NTOT - g0; if (nn > 1024) nn = 1024;
    int s = bbs[b];
    int e = s + bucketCount[b];

    #pragma unroll
    for (int i = t; i < 1024; i += 256) cnt[i] = 0;
    __syncthreads();
    for (int i = s + t; i < e; i += 256) atomicAdd(&cnt[(int)stage[i].x - g0], 1);
    __syncthreads();
    int loc[4]; int ss = 0;
    #pragma unroll
    for (int j = 0; j < 4; j++) { loc[j] = cnt[t*4 + j]; ss += loc[j]; }
    part[t] = ss;
    __syncthreads();
    for (int o = 1; o < 256; o <<= 1) {
        int x = (t >= o) ? part[t - o] : 0;
        __syncthreads();
        part[t] += x;
        __syncthreads();
    }
    int run = (t > 0) ? part[t-1] : 0;
    #pragma unroll
    for (int j = 0; j < 4; j++) { int c = loc[j]; cnt[t*4 + j] = run; run += c; }
    __syncthreads();
    for (int i = t; i < nn; i += 256) rowAll[g0 + i] = s + cnt[i];
    if (b == NB-1 && t == 0) rowAll[NTOT] = 3*NEDGE;
    __syncthreads();
    for (int i = s + t; i < e; i += 256) {
        uint2 ed = stage[i];
        int slot = atomicAdd(&cnt[(int)ed.x - g0], 1);
        colAll[s + slot] = (int)ed.y;
    }
}

// ---------------------------------------------------------------------------
// Gather-mean (proven round-10 shape): 16 lanes/node, uint4 (16B) row chunks,
// 4-deep load pipeline, dual accumulators -> 16 outstanding row-loads/wave.
__device__ __forceinline__ void acc8(float* a, uint4 v) {
    a[0] += b2f(v.x & 0xffffu); a[1] += b2f(v.x >> 16);
    a[2] += b2f(v.y & 0xffffu); a[3] += b2f(v.y >> 16);
    a[4] += b2f(v.z & 0xffffu); a[5] += b2f(v.z >> 16);
    a[6] += b2f(v.w & 0xffffu); a[7] += b2f(v.w >> 16);
}

__global__ __launch_bounds__(256) void gather_seg(
    int g0, int g1,
    const ushort* __restrict__ xp, const ushort* __restrict__ xa,
    const int* __restrict__ rowAll, const int* __restrict__ colAll,
    ushort* __restrict__ aggC, ushort* __restrict__ aggW,
    ushort* __restrict__ aggR)
{
    int idx = blockIdx.x * 256 + threadIdx.x;
    int g = g0 + (idx >> 4);
    int lane = idx & 15;
    if (g >= g1) return;
    const ushort* xs; ushort* out; int node;
    if (g < NPAPER)        { node = g;            xs = xp; out = aggC; }
    else if (g < 2*NPAPER) { node = g - NPAPER;   xs = xa; out = aggW; }
    else                   { node = g - 2*NPAPER; xs = xp; out = aggR; }

    int s = rowAll[g], e = rowAll[g + 1];
    float a[8] = {0,0,0,0,0,0,0,0};
    float b[8] = {0,0,0,0,0,0,0,0};
    int j = s;
    #pragma unroll 1
    for (; j + 4 <= e; j += 4) {
        int s0 = colAll[j], s1 = colAll[j+1], s2 = colAll[j+2], s3 = colAll[j+3];
        uint4 v0 = *(const uint4*)(xs + (size_t)s0 * DIM + lane * 8);
        uint4 v1 = *(const uint4*)(xs + (size_t)s1 * DIM + lane * 8);
        uint4 v2 = *(const uint4*)(xs + (size_t)s2 * DIM + lane * 8);
        uint4 v3 = *(const uint4*)(xs + (size_t)s3 * DIM + lane * 8);
        acc8(a, v0);
        acc8(b, v1);
        acc8(a, v2);
        acc8(b, v3);
    }
    #pragma unroll 1
    for (; j < e; j++) {
        uint4 v0 = *(const uint4*)(xs + (size_t)colAll[j] * DIM + lane * 8);
        acc8(a, v0);
    }
    float inv = (e > s) ? 1.f / (float)(e - s) : 0.f;
    #pragma unroll
    for (int i = 0; i < 8; i++) a[i] = (a[i] + b[i]) * inv;
    uint4 o;
    o.x = (uint)f2b(a[0]) | ((uint)f2b(a[1]) << 16);
    o.y = (uint)f2b(a[2]) | ((uint)f2b(a[3]) << 16);
    o.z = (uint)f2b(a[4]) | ((uint)f2b(a[5]) << 16);
    o.w = (uint)f2b(a[6]) | ((uint)f2b(a[7]) << 16);
    *(uint4*)(out + (size_t)node * DIM + lane * 8) = o;
}

// ---------------------------------------------------------------------------
// Merged MFMA GEMM + bias + LayerNorm + ReLU, 256-ROW tiles, 8 waves (512 thr).
// Blocks [0,pblk): paper rows (K=384, segs aggC|aggW|self-p); blocks [pblk,..):
// author rows (K=256, segs aggR|self-a).  Wave w owns rows w*32..w*32+31
// (rowblocks 2w, 2w+1).  LDS: As 32 KB ([ks2][rb16][lane64][8]) + Bs 16 KB.
// Per K-step: 6 global_load_lds/thread, 2 barriers, 32 MFMA/wave — half the
// barrier+stage cost per output row vs the 128-row version.
__global__ __launch_bounds__(512) void gemm_ln2(
    const ushort* __restrict__ aggC, const ushort* __restrict__ aggW,
    const ushort* __restrict__ aggR,
    const ushort* __restrict__ xp, const ushort* __restrict__ xa,
    const ushort* __restrict__ Btp, const ushort* __restrict__ Bta,
    const float* __restrict__ biasp, const float* __restrict__ biasa,
    const float* __restrict__ lns, const float* __restrict__ lnb,
    ushort* __restrict__ outp, ushort* __restrict__ outa, int pblk)
{
    __shared__ ushort As[16384];  // 32 KB, one K-step, 256 rows
    __shared__ ushort Bs[8192];   // 16 KB

    bool isp = (int)blockIdx.x < pblk;
    int  bid = isp ? blockIdx.x : (blockIdx.x - pblk);
    int  N   = isp ? NPAPER : NAUTH;
    int  K   = isp ? 384 : 256;
    const ushort* A0 = isp ? aggC : aggR;
    const ushort* A1 = isp ? aggW : xa;
    const ushort* A2 = isp ? xp   : xa;
    const ushort* Bt = isp ? Btp  : Bta;
    const float* bias = isp ? biasp : biasa;
    const float* lng  = lns + (isp ? 0 : 128);
    const float* lnbb = lnb + (isp ? 0 : 128);
    ushort* out = isp ? outp : outa;

    int t    = threadIdx.x;
    int w    = t >> 6;            // 0..7
    int lane = t & 63;
    int row0 = bid * 256;
    int l15  = lane & 15;
    int g4   = lane >> 4;

    f32x4 acc0[8], acc1[8];
    #pragma unroll
    for (int f = 0; f < 8; f++) {
        acc0[f] = (f32x4){0.f, 0.f, 0.f, 0.f};
        acc1[f] = (f32x4){0.f, 0.f, 0.f, 0.f};
    }

    int nstep = K >> 6;
    for (int st = 0; st < nstep; st++) {
        int kk  = st << 6;
        int seg = kk >> 7, kl = kk & 127;
        const ushort* Ap = (seg == 0) ? A0 : ((seg == 1) ? A1 : A2);

        // stage A: 2048 chunks of 16B in [ks(2)][rb(16)][lane(64)] order.
        #pragma unroll
        for (int p = 0; p < 4; p++) {
            int q  = p*512 + t;
            int ks = q >> 10, rb = (q >> 6) & 15, l = q & 63;
            int row = row0 + rb*16 + (l & 15);
            row = (row < N) ? row : (N - 1);
            int k = kl + ks*32 + (l >> 4)*8;
            int qbase = p*512 + w*64;
            GLD_LDS16(Ap + (size_t)row*DIM + k, As + qbase*8);
        }
        // stage B: linear copy of 16 KB from packed Bt.
        #pragma unroll
        for (int p = 0; p < 2; p++) {
            int q = p*512 + t;
            int qbase = p*512 + w*64;
            GLD_LDS16(Bt + ((size_t)st*8192 + (size_t)q*8), Bs + qbase*8);
        }
        __syncthreads();

        #pragma unroll
        for (int ks = 0; ks < 2; ks++) {
            short8 a0 = *(const short8*)(&As[((ks*16 + w*2 + 0)*64 + lane)*8]);
            short8 a1 = *(const short8*)(&As[((ks*16 + w*2 + 1)*64 + lane)*8]);
            #pragma unroll
            for (int f = 0; f < 8; f++) {
                short8 bv = *(const short8*)(&Bs[((ks*8 + f)*64 + lane)*8]);
                acc0[f] = __builtin_amdgcn_mfma_f32_16x16x32_bf16(a0, bv, acc0[f], 0, 0, 0);
                acc1[f] = __builtin_amdgcn_mfma_f32_16x16x32_bf16(a1, bv, acc1[f], 0, 0, 0);
            }
        }
        __syncthreads();
    }

    float bv[8], gv[8], bbv[8];
    #pragma unroll
    for (int f = 0; f < 8; f++) {
        bv[f]  = bias[f*16 + l15];
        gv[f]  = lng [f*16 + l15];
        bbv[f] = lnbb[f*16 + l15];
    }
    #pragma unroll
    for (int r2 = 0; r2 < 2; r2++) {
        #pragma unroll
        for (int i = 0; i < 4; i++) {
            int grow = row0 + w*32 + r2*16 + g4*4 + i;
            float vv[8];
            float s = 0.f, sq = 0.f;
            #pragma unroll
            for (int f = 0; f < 8; f++) {
                float av = r2 ? acc1[f][i] : acc0[f][i];
                vv[f] = av + bv[f];
                s  += vv[f];
                sq += vv[f] * vv[f];
            }
            s += __shfl_xor(s, 1);  sq += __shfl_xor(sq, 1);
            s += __shfl_xor(s, 2);  sq += __shfl_xor(sq, 2);
            s += __shfl_xor(s, 4);  sq += __shfl_xor(sq, 4);
            s += __shfl_xor(s, 8);  sq += __shfl_xor(sq, 8);
            float m   = s * (1.f/128.f);
            float var = sq * (1.f/128.f) - m*m;
            float rr  = rsqrtf(var + 1e-5f);
            if (grow < N) {
                #pragma unroll
                for (int f = 0; f < 8; f++) {
                    float y = (vv[f] - m) * rr * gv[f] + bbv[f];
                    y = fmaxf(y, 0.f);
                    out[(size_t)grow*DIM + f*16 + l15] = f2b(y);
                }
            }
        }
    }
}

// ---------------------------------------------------------------------------
// Head: out[N][16] = xp(bf16)[N][128] @ Wh[128][16] + bh.  16 rows/block.
__global__ __launch_bounds__(256) void head_kernel(
    const ushort* __restrict__ xp, const float* __restrict__ Wh,
    const float* __restrict__ bh, float* __restrict__ out)
{
    __shared__ float Xs[16*128];
    __shared__ float Ws[128*16];
    int t = threadIdx.x;
    int row0 = blockIdx.x * 16;
    for (int i = t; i < 2048; i += 256) Ws[i] = Wh[i];
    {
        int r = t >> 4, k8 = (t & 15) * 8;
        int gr = row0 + r;
        if (gr < NPAPER) {
            uint4 v = *(const uint4*)(xp + (size_t)gr*DIM + k8);
            const ushort* pv = (const ushort*)&v;
            #pragma unroll
            for (int i = 0; i < 8; i++) Xs[r*128 + k8 + i] = b2f(pv[i]);
        } else {
            #pragma unroll
            for (int i = 0; i < 8; i++) Xs[r*128 + k8 + i] = 0.f;
        }
    }
    __syncthreads();
    int r = t >> 4, c = t & 15;
    float acc = bh[c];
    #pragma unroll 16
    for (int k = 0; k < 128; k++) acc += Xs[r*128 + k] * Ws[k*16 + c];
    int gr = row0 + r;
    if (gr < NPAPER) out[(size_t)gr*NCLS + c] = acc;
}

// ---------------------------------------------------------------------------
extern "C" void kernel_launch(void* const* d_in, const int* in_sizes, int n_in,
                              void* d_out, int out_size, void* d_ws, size_t ws_size,
                              hipStream_t stream)
{
    const float* x_paper  = (const float*)d_in[0];
    const float* x_author = (const float*)d_in[1];
    const int*   ei_cites = (const int*)d_in[2];
    const int*   ei_writes= (const int*)d_in[3];
    const int*   ei_rev   = (const int*)d_in[4];
    const float* Wl       = (const float*)d_in[5];
    const float* Wr       = (const float*)d_in[6];
    const float* bl       = (const float*)d_in[7];
    const float* linp     = (const float*)d_in[8];
    const float* lina     = (const float*)d_in[9];
    const float* ln_s     = (const float*)d_in[10];
    const float* ln_b     = (const float*)d_in[11];
    const float* Wh       = (const float*)d_in[12];
    const float* bh       = (const float*)d_in[13];
    float* out = (float*)d_out;

    float* ws = (float*)d_ws;
    size_t off = 0;
    float* Bp     = ws + off; off += 2*384*128;
    float* Ba     = ws + off; off += 2*256*128;
    float* biasp  = ws + off; off += 2*128;
    float* biasa  = ws + off; off += 2*128;
    float* biasp2 = ws + off; off += 2*128;
    float* biasa2 = ws + off; off += 2*128;

    ushort* uws = (ushort*)(ws + off);
    size_t uoff = 0;
    ushort* xpb0 = uws + uoff; uoff += (size_t)NPAPER * DIM;
    ushort* xab0 = uws + uoff; uoff += (size_t)NAUTH  * DIM;
    ushort* xpb1 = uws + uoff; uoff += (size_t)NPAPER * DIM;
    ushort* xab1 = uws + uoff; uoff += (size_t)NAUTH  * DIM;
    ushort* aggC = uws + uoff; uoff += (size_t)NPAPER * DIM;
    ushort* aggW = uws + uoff; uoff += (size_t)NPAPER * DIM;
    ushort* aggR = uws + uoff; uoff += (size_t)NAUTH  * DIM;
    ushort* Btp  = uws + uoff; uoff += 2*49152;
    ushort* Bta  = uws + uoff; uoff += 2*32768;
    if (uoff & 3) uoff += 4 - (uoff & 3);   // 8B-align what follows

    uint2* stage = (uint2*)(uws + uoff);    // 3E uint2 = 12 MB
    int* iws = (int*)(stage + 3*NEDGE);
    size_t ioff = 0;
    int* rowAll      = iws + ioff; ioff += NTOT + 1;
    int* colAll      = iws + ioff; ioff += 3*NEDGE;
    int* bucketCount = iws + ioff; ioff += 256;
    int* emitCursor  = iws + ioff; ioff += 256;   // contiguous with bucketCount

    const int TOBF = (NPAPER + NAUTH) * DIM / 4 / 256;   // 18750

    // L0: bucket_count ∥ prep_weights ∥ to_bf16   (zero bucketCount+emitCursor)
    hipMemsetAsync(bucketCount, 0, 512*4, stream);
    misc0<<<NBLK_A + PREPB + TOBF, 256, 0, stream>>>(
        ei_cites, ei_writes, ei_rev, bucketCount,
        Wl, Wr, bl, Bp, Ba, biasp, biasa,
        x_paper, x_author, xpb0, xab0);
    // L1: fold_bias ∥ build_bt ∥ bucket_emit (scan inlined per block)
    misc1<<<2 + BTB + NBLK_A, 256, 0, stream>>>(
        biasp, biasa, linp, lina, biasp2, biasa2,
        Bp, Ba, Btp, Bta,
        ei_cites, ei_writes, ei_rev,
        bucketCount, emitCursor, stage);
    // L2: CSR finalize (scan inlined)
    csr_fillB<<<NB, 256, 0, stream>>>(stage, bucketCount, rowAll, colAll);

    // ---- layer 0 ----
    gather_seg<<<(size_t)NTOT*16/256, 256, 0, stream>>>(
        0, NTOT, xpb0, xab0, rowAll, colAll, aggC, aggW, aggR);
    gemm_ln2<<<PBLK2 + ABLK2, 512, 0, stream>>>(
        aggC, aggW, aggR, xpb0, xab0,
        Btp, Bta, biasp2, biasa2, ln_s, ln_b,
        xpb1, xab1, PBLK2);

    // ---- layer 1 (author path dead: only C+W gathers, paper GEMM) ----
    gather_seg<<<(size_t)2*NPAPER*16/256, 256, 0, stream>>>(
        0, 2*NPAPER, xpb1, xab1, rowAll, colAll, aggC, aggW, aggR);
    gemm_ln2<<<PBLK2, 512, 0, stream>>>(
        aggC, aggW, aggR, xpb1, xab1,
        Btp + 49152, Bta + 32768, biasp2 + 128, biasa2 + 128,
        ln_s + 256, ln_b + 256,
        xpb0, xab0, PBLK2);

    // head on layer-1 paper output
    head_kernel<<<(NPAPER + 15)/16, 256, 0, stream>>>(xpb0, Wh, bh, out);
}

// Round 15
// 302.340 us; speedup vs baseline: 1.0259x; 1.0259x over previous
//
#include <hip/hip_runtime.h>
#include <math.h>

#define NPAPER 100000
#define NAUTH  50000
#define DIM    128
#define NEDGE  500000
#define NCLS   16
#define NTOT   (2*NPAPER + NAUTH)   // concatenated CSR node space (C | W | R)
#define NB     245                  // buckets of 1024 nodes over NTOT
#define CHUNK_A 11776               // edges per bucketize block
#define NBLK_A  128                 // ceil(3*NEDGE / CHUNK_A)
#define PBLK   ((NPAPER + 127) / 128)   // 782
#define ABLK   ((NAUTH  + 127) / 128)   // 391

typedef unsigned int   uint;
typedef unsigned short ushort;
typedef unsigned char  uchar;
using short8 = __attribute__((ext_vector_type(8))) short;
using f32x4  = __attribute__((ext_vector_type(4))) float;

__device__ __forceinline__ float b2f(uint u) {
    return __uint_as_float(u << 16);
}
__device__ __forceinline__ ushort f2b(float f) {   // round-to-nearest-even
    uint x = __float_as_uint(f);
    return (ushort)((x + 0x7fffu + ((x >> 16) & 1u)) >> 16);
}

// global_load_lds: linear LDS dest (wave base + lane*16), per-lane global src.
#define GLD_LDS16(srcp, ldsp) \
    __builtin_amdgcn_global_load_lds( \
        (const __attribute__((address_space(1))) void*)(srcp), \
        (__attribute__((address_space(3))) void*)(ldsp), 16, 0, 0)

// ---------------------------------------------------------------------------
// prep bodies (block-indexed device functions, merged into lean misc kernels)
// ---------------------------------------------------------------------------
__device__ __forceinline__ void prep_weights_body(int b, int tid,
    const float* __restrict__ Wl, const float* __restrict__ Wr,
    const float* __restrict__ bl,
    float* __restrict__ Bp, float* __restrict__ Ba,
    float* __restrict__ biasp, float* __restrict__ biasa)
{
    int t = b * 256 + tid;
    if (t < 2*384*128) {
        int l = t / (384*128); int rem = t - l*(384*128);
        int k = rem >> 7, j = rem & 127;
        float v;
        if (k < 128)      v = Wl[((l*3+0)*128 + j)*128 + k];
        else if (k < 256) v = Wl[((l*3+1)*128 + j)*128 + (k-128)];
        else              v = Wr[((l*3+0)*128 + j)*128 + (k-256)]
                            + Wr[((l*3+1)*128 + j)*128 + (k-256)];
        Bp[t] = v;
        return;
    }
    t -= 2*384*128;
    if (t < 2*256*128) {
        int l = t / (256*128); int rem = t - l*(256*128);
        int k = rem >> 7, j = rem & 127;
        Ba[t] = (k < 128) ? Wl[((l*3+2)*128 + j)*128 + k]
                          : Wr[((l*3+2)*128 + j)*128 + (k-128)];
        return;
    }
    t -= 2*256*128;
    if (t < 256) { int l=t>>7, j=t&127; biasp[t] = bl[(l*3+0)*128+j] + bl[(l*3+1)*128+j]; return; }
    t -= 256;
    if (t < 256) { int l=t>>7, j=t&127; biasa[t] = bl[(l*3+2)*128+j]; return; }
}

// residual fold + bf16 + PACK into MFMA-fragment order.
__device__ __forceinline__ size_t pack_off(int j, int k) {
    int kstep = k >> 6, ks = (k >> 5) & 1, g4 = (k >> 3) & 3, jj = k & 7;
    int f = j >> 4, l15 = j & 15;
    return (size_t)kstep*8192 + (size_t)(ks*512 + f*64 + g4*16 + l15)*8 + jj;
}

__device__ __forceinline__ void build_bt_body(int b, int tid,
    const float* __restrict__ Bp, const float* __restrict__ Ba,
    const float* __restrict__ linp, const float* __restrict__ lina,
    ushort* __restrict__ Btp, ushort* __restrict__ Bta)
{
    int t = b * 256 + tid;
    if (t < 2*128*384) {
        int l = t / (128*384); int rem = t - l*(128*384);
        int j = rem / 384, k = rem - j*384;
        const float* brow = Bp + (size_t)l*384*128 + (size_t)k*128;
        float v = brow[j];
        if (l == 0) {
            const float* lrow = linp + (size_t)j*128;
            float s = 0.f;
            #pragma unroll 8
            for (int m = 0; m < 128; m++) s += brow[m] * lrow[m];
            v += s;
        }
        Btp[(size_t)l*49152 + pack_off(j, k)] = f2b(v);
        return;
    }
    t -= 2*128*384;
    if (t < 2*128*256) {
        int l = t / (128*256); int rem = t - l*(128*256);
        int j = rem / 256, k = rem - j*256;
        const float* brow = Ba + (size_t)l*256*128 + (size_t)k*128;
        float v = brow[j];
        if (l == 0) {
            const float* lrow = lina + (size_t)j*128;
            float s = 0.f;
            #pragma unroll 8
            for (int m = 0; m < 128; m++) s += brow[m] * lrow[m];
            v += s;
        }
        Bta[(size_t)l*32768 + pack_off(j, k)] = f2b(v);
    }
}

__device__ __forceinline__ void fold_bias_body(int b, int tid,
    const float* __restrict__ biasp, const float* __restrict__ biasa,
    const float* __restrict__ linp, const float* __restrict__ lina,
    float* __restrict__ biasp2, float* __restrict__ biasa2)
{
    int t = b * 256 + tid;   // 512 total
    int isa = t >> 8; int r = t & 255;
    int l = r >> 7, j = r & 127;
    const float* bsrc = isa ? biasa : biasp;
    const float* lin  = isa ? lina  : linp;
    float v = bsrc[r];
    if (l == 0) {
        float s = 0.f;
        for (int k = 0; k < 128; k++) s += bsrc[k] * lin[j*128 + k];
        v += s;
    }
    (isa ? biasa2 : biasp2)[r] = v;
}

__device__ __forceinline__ void to_bf16_body(int b, int tid,
    const float* __restrict__ xp, const float* __restrict__ xa,
    ushort* __restrict__ yp, ushort* __restrict__ ya)
{
    int i = b * 256 + tid;
    const int n4p = NPAPER * DIM / 4;
    const float* x; ushort* y;
    if (i < n4p) { x = xp; y = yp; }
    else { x = xa; y = ya; i -= n4p; }
    float4 v = ((const float4*)x)[i];
    uint2 o;
    o.x = (uint)f2b(v.x) | ((uint)f2b(v.y) << 16);
    o.y = (uint)f2b(v.z) | ((uint)f2b(v.w) << 16);
    ((uint2*)y)[i] = o;
}

// ---------------------------------------------------------------------------
__device__ __forceinline__ int edge_g(const int* __restrict__ eiC,
                                      const int* __restrict__ eiW,
                                      const int* __restrict__ eiR, int i)
{
    int tpe = (i >= 2*NEDGE) ? 2 : ((i >= NEDGE) ? 1 : 0);
    int e = i - tpe*NEDGE;
    const int* ei = (tpe == 0) ? eiC : ((tpe == 1) ? eiW : eiR);
    int base = (tpe == 0) ? 0 : ((tpe == 1) ? NPAPER : 2*NPAPER);
    return base + ei[NEDGE + e];
}

// misc0: [bucket_count (128) | prep_weights (642) | to_bf16 (18750)]
#define PREPB 642
__global__ __launch_bounds__(256) void misc0(
    const int* __restrict__ eiC, const int* __restrict__ eiW,
    const int* __restrict__ eiR, int* __restrict__ bucketCount,
    const float* __restrict__ Wl, const float* __restrict__ Wr,
    const float* __restrict__ bl,
    float* __restrict__ Bp, float* __restrict__ Ba,
    float* __restrict__ biasp, float* __restrict__ biasa,
    const float* __restrict__ xpf, const float* __restrict__ xaf,
    ushort* __restrict__ xpb, ushort* __restrict__ xab)
{
    __shared__ int h[256];
    int b = blockIdx.x, t = threadIdx.x;
    if (b < NBLK_A) {
        h[t] = 0;
        __syncthreads();
        int start = b * CHUNK_A;
        int n = 3*NEDGE - start; if (n > CHUNK_A) n = CHUNK_A;
        for (int i = t; i < n; i += 256)
            atomicAdd(&h[edge_g(eiC, eiW, eiR, start + i) >> 10], 1);
        __syncthreads();
        if (h[t]) atomicAdd(&bucketCount[t], h[t]);
        return;
    }
    b -= NBLK_A;
    if (b < PREPB) {
        prep_weights_body(b, t, Wl, Wr, bl, Bp, Ba, biasp, biasa);
        return;
    }
    b -= PREPB;
    to_bf16_body(b, t, xpf, xaf, xpb, xab);
}

// misc1: [fold_bias (2) | build_bt (640) | bucket_emit (128)]
#define BTB 640
__global__ __launch_bounds__(256) void misc1(
    const float* __restrict__ biasp, const float* __restrict__ biasa,
    const float* __restrict__ linp, const float* __restrict__ lina,
    float* __restrict__ biasp2, float* __restrict__ biasa2,
    const float* __restrict__ Bp, const float* __restrict__ Ba,
    ushort* __restrict__ Btp, ushort* __restrict__ Bta,
    const int* __restrict__ eiC, const int* __restrict__ eiW,
    const int* __restrict__ eiR,
    const int* __restrict__ bucketCount, int* __restrict__ emitCursor,
    uint2* __restrict__ stage)
{
    int blk = blockIdx.x, t = threadIdx.x;
    if (blk < 2) {
        fold_bias_body(blk, t, biasp, biasa, linp, lina, biasp2, biasa2);
        return;
    }
    blk -= 2;
    if (blk < BTB) {
        build_bt_body(blk, t, Bp, Ba, linp, lina, Btp, Bta);
        return;
    }
    int b = blk - BTB;

    __shared__ uchar  bId [CHUNK_A];
    __shared__ ushort rnk [CHUNK_A];
    __shared__ ushort perm[CHUNK_A];
    __shared__ uchar  posB[CHUNK_A];
    __shared__ int lcnt[256];
    __shared__ int lpre[256];
    __shared__ int bbase[256];
    __shared__ int bbs[256];

    // redundant exclusive scan of bucketCount -> bucket bases
    {
        int v = (t < NB) ? bucketCount[t] : 0;
        bbs[t] = v;
        __syncthreads();
        for (int o = 1; o < 256; o <<= 1) {
            int x = (t >= o) ? bbs[t - o] : 0;
            __syncthreads();
            bbs[t] += x;
            __syncthreads();
        }
        int inc = bbs[t];
        __syncthreads();
        bbs[t] = inc - ((t < NB) ? bucketCount[t] : 0);   // exclusive
        __syncthreads();
    }

    int start = b * CHUNK_A;
    int n = 3*NEDGE - start; if (n > CHUNK_A) n = CHUNK_A;
    lcnt[t] = 0;
    __syncthreads();
    for (int i = t; i < n; i += 256) {
        int bb = edge_g(eiC, eiW, eiR, start + i) >> 10;
        bId[i] = (uchar)bb;
        rnk[i] = (ushort)atomicAdd(&lcnt[bb], 1);
    }
    __syncthreads();
    lpre[t] = lcnt[t];
    __syncthreads();
    for (int o = 1; o < 256; o <<= 1) {
        int x = (t >= o) ? lpre[t - o] : 0;
        __syncthreads();
        lpre[t] += x;
        __syncthreads();
    }
    if (lcnt[t] > 0) bbase[t] = bbs[t] + atomicAdd(&emitCursor[t], lcnt[t]);
    __syncthreads();
    for (int i = t; i < n; i += 256) {
        int bb = bId[i];
        int p = (lpre[bb] - lcnt[bb]) + rnk[i];
        perm[p] = (ushort)i;
        posB[p] = (uchar)bb;
    }
    __syncthreads();
    for (int p = t; p < n; p += 256) {
        int bb = posB[p];
        int i = start + perm[p];
        int tpe = (i >= 2*NEDGE) ? 2 : ((i >= NEDGE) ? 1 : 0);
        int e = i - tpe*NEDGE;
        const int* ei = (tpe == 0) ? eiC : ((tpe == 1) ? eiW : eiR);
        int base = (tpe == 0) ? 0 : ((tpe == 1) ? NPAPER : 2*NPAPER);
        uint2 o2;
        o2.x = (uint)(base + ei[NEDGE + e]);
        o2.y = (uint)ei[e];
        stage[bbase[bb] + (p - (lpre[bb] - lcnt[bb]))] = o2;
    }
}

// Per-bucket CSR finalize; bucket bases scanned inline from bucketCount.
__global__ __launch_bounds__(256) void csr_fillB(
    const uint2* __restrict__ stage, const int* __restrict__ bucketCount,
    int* __restrict__ rowAll, int* __restrict__ colAll)
{
    __shared__ int cnt[1024];
    __shared__ int part[256];
    __shared__ int bbs[256];
    int b = blockIdx.x;
    int t = threadIdx.x;

    // inline exclusive scan of bucketCount
    {
        int v = (t < NB) ? bucketCount[t] : 0;
        bbs[t] = v;
        __syncthreads();
        for (int o = 1; o < 256; o <<= 1) {
            int x = (t >= o) ? bbs[t - o] : 0;
            __syncthreads();
            bbs[t] += x;
            __syncthreads();
        }
        int inc = bbs[t];
        __syncthreads();
        bbs[t] = inc - ((t < NB) ? bucketCount[t] : 0);
        __syncthreads();
    }
    int g0 = b << 10;
    int nn = NTOT - g0; if (nn > 1024) nn = 1024;
    int s = bbs[b];
    int e = s + bucketCount[b];

    #pragma unroll
    for (int i = t; i < 1024; i += 256) cnt[i] = 0;
    __syncthreads();
    for (int i = s + t; i < e; i += 256) atomicAdd(&cnt[(int)stage[i].x - g0], 1);
    __syncthreads();
    int loc[4]; int ss = 0;
    #pragma unroll
    for (int j = 0; j < 4; j++) { loc[j] = cnt[t*4 + j]; ss += loc[j]; }
    part[t] = ss;
    __syncthreads();
    for (int o = 1; o < 256; o <<= 1) {
        int x = (t >= o) ? part[t - o] : 0;
        __syncthreads();
        part[t] += x;
        __syncthreads();
    }
    int run = (t > 0) ? part[t-1] : 0;
    #pragma unroll
    for (int j = 0; j < 4; j++) { int c = loc[j]; cnt[t*4 + j] = run; run += c; }
    __syncthreads();
    for (int i = t; i < nn; i += 256) rowAll[g0 + i] = s + cnt[i];
    if (b == NB-1 && t == 0) rowAll[NTOT] = 3*NEDGE;
    __syncthreads();
    for (int i = s + t; i < e; i += 256) {
        uint2 ed = stage[i];
        int slot = atomicAdd(&cnt[(int)ed.x - g0], 1);
        colAll[s + slot] = (int)ed.y;
    }
}

// ---------------------------------------------------------------------------
// Gather-mean (proven round-10 shape): 16 lanes/node, uint4 (16B) row chunks,
// 4-deep load pipeline, dual accumulators -> 16 outstanding row-loads/wave.
__device__ __forceinline__ void acc8(float* a, uint4 v) {
    a[0] += b2f(v.x & 0xffffu); a[1] += b2f(v.x >> 16);
    a[2] += b2f(v.y & 0xffffu); a[3] += b2f(v.y >> 16);
    a[4] += b2f(v.z & 0xffffu); a[5] += b2f(v.z >> 16);
    a[6] += b2f(v.w & 0xffffu); a[7] += b2f(v.w >> 16);
}

__global__ __launch_bounds__(256) void gather_seg(
    int g0, int g1,
    const ushort* __restrict__ xp, const ushort* __restrict__ xa,
    const int* __restrict__ rowAll, const int* __restrict__ colAll,
    ushort* __restrict__ aggC, ushort* __restrict__ aggW,
    ushort* __restrict__ aggR)
{
    int idx = blockIdx.x * 256 + threadIdx.x;
    int g = g0 + (idx >> 4);
    int lane = idx & 15;
    if (g >= g1) return;
    const ushort* xs; ushort* out; int node;
    if (g < NPAPER)        { node = g;            xs = xp; out = aggC; }
    else if (g < 2*NPAPER) { node = g - NPAPER;   xs = xa; out = aggW; }
    else                   { node = g - 2*NPAPER; xs = xp; out = aggR; }

    int s = rowAll[g], e = rowAll[g + 1];
    float a[8] = {0,0,0,0,0,0,0,0};
    float b[8] = {0,0,0,0,0,0,0,0};
    int j = s;
    #pragma unroll 1
    for (; j + 4 <= e; j += 4) {
        int s0 = colAll[j], s1 = colAll[j+1], s2 = colAll[j+2], s3 = colAll[j+3];
        uint4 v0 = *(const uint4*)(xs + (size_t)s0 * DIM + lane * 8);
        uint4 v1 = *(const uint4*)(xs + (size_t)s1 * DIM + lane * 8);
        uint4 v2 = *(const uint4*)(xs + (size_t)s2 * DIM + lane * 8);
        uint4 v3 = *(const uint4*)(xs + (size_t)s3 * DIM + lane * 8);
        acc8(a, v0);
        acc8(b, v1);
        acc8(a, v2);
        acc8(b, v3);
    }
    #pragma unroll 1
    for (; j < e; j++) {
        uint4 v0 = *(const uint4*)(xs + (size_t)colAll[j] * DIM + lane * 8);
        acc8(a, v0);
    }
    float inv = (e > s) ? 1.f / (float)(e - s) : 0.f;
    #pragma unroll
    for (int i = 0; i < 8; i++) a[i] = (a[i] + b[i]) * inv;
    uint4 o;
    o.x = (uint)f2b(a[0]) | ((uint)f2b(a[1]) << 16);
    o.y = (uint)f2b(a[2]) | ((uint)f2b(a[3]) << 16);
    o.z = (uint)f2b(a[4]) | ((uint)f2b(a[5]) << 16);
    o.w = (uint)f2b(a[6]) | ((uint)f2b(a[7]) << 16);
    *(uint4*)(out + (size_t)node * DIM + lane * 8) = o;
}

// ---------------------------------------------------------------------------
// Merged MFMA GEMM + bias + LayerNorm + ReLU (128-row tiles, proven config).
// FUSE_HEAD=1 (l1 paper launch): skips the activation store and computes
// head = relu'd_row @ Wh + bh directly in the epilogue (Wh staged in LDS,
// stride-20 padded; 16-lane butterfly reduce; lane l15==0 writes 64B/row).
template<int FUSE_HEAD>
__global__ __launch_bounds__(256) void gemm_ln2(
    const ushort* __restrict__ aggC, const ushort* __restrict__ aggW,
    const ushort* __restrict__ aggR,
    const ushort* __restrict__ xp, const ushort* __restrict__ xa,
    const ushort* __restrict__ Btp, const ushort* __restrict__ Bta,
    const float* __restrict__ biasp, const float* __restrict__ biasa,
    const float* __restrict__ lns, const float* __restrict__ lnb,
    ushort* __restrict__ outp, ushort* __restrict__ outa, int pblk,
    const float* __restrict__ Wh, const float* __restrict__ bh,
    float* __restrict__ hout)
{
    __shared__ ushort As[8192];   // 16 KB, one K-step
    __shared__ ushort Bs[8192];   // 16 KB

    bool isp = (int)blockIdx.x < pblk;
    int  bid = isp ? blockIdx.x : (blockIdx.x - pblk);
    int  N   = isp ? NPAPER : NAUTH;
    int  K   = isp ? 384 : 256;
    const ushort* A0 = isp ? aggC : aggR;
    const ushort* A1 = isp ? aggW : xa;
    const ushort* A2 = isp ? xp   : xa;
    const ushort* Bt = isp ? Btp  : Bta;
    const float* bias = isp ? biasp : biasa;
    const float* lng  = lns + (isp ? 0 : 128);
    const float* lnbb = lnb + (isp ? 0 : 128);
    ushort* out = isp ? outp : outa;

    int t    = threadIdx.x;
    int w    = t >> 6;
    int lane = t & 63;
    int row0 = bid * 128;
    int l15  = lane & 15;
    int g4   = lane >> 4;

    f32x4 acc0[8], acc1[8];
    #pragma unroll
    for (int f = 0; f < 8; f++) {
        acc0[f] = (f32x4){0.f, 0.f, 0.f, 0.f};
        acc1[f] = (f32x4){0.f, 0.f, 0.f, 0.f};
    }

    int nstep = K >> 6;
    for (int st = 0; st < nstep; st++) {
        int kk  = st << 6;
        int seg = kk >> 7, kl = kk & 127;
        const ushort* Ap = (seg == 0) ? A0 : ((seg == 1) ? A1 : A2);

        #pragma unroll
        for (int p = 0; p < 4; p++) {
            int q  = p*256 + t;
            int ks = q >> 9, rb = (q >> 6) & 7, l = q & 63;
            int row = row0 + rb*16 + (l & 15);
            row = (row < N) ? row : (N - 1);
            int k = kl + ks*32 + (l >> 4)*8;
            int qbase = p*256 + w*64;
            GLD_LDS16(Ap + (size_t)row*DIM + k, As + qbase*8);
        }
        #pragma unroll
        for (int p = 0; p < 4; p++) {
            int q = p*256 + t;
            int qbase = p*256 + w*64;
            GLD_LDS16(Bt + ((size_t)st*8192 + (size_t)q*8), Bs + qbase*8);
        }
        __syncthreads();

        #pragma unroll
        for (int ks = 0; ks < 2; ks++) {
            short8 a0 = *(const short8*)(&As[((ks*8 + w*2 + 0)*64 + lane)*8]);
            short8 a1 = *(const short8*)(&As[((ks*8 + w*2 + 1)*64 + lane)*8]);
            #pragma unroll
            for (int f = 0; f < 8; f++) {
                short8 bv = *(const short8*)(&Bs[((ks*8 + f)*64 + lane)*8]);
                acc0[f] = __builtin_amdgcn_mfma_f32_16x16x32_bf16(a0, bv, acc0[f], 0, 0, 0);
                acc1[f] = __builtin_amdgcn_mfma_f32_16x16x32_bf16(a1, bv, acc1[f], 0, 0, 0);
            }
        }
        __syncthreads();
    }

    float* Whs = (float*)As;   // 128 rows x 20 floats (10 KB), FUSE_HEAD only
    if (FUSE_HEAD) {
        for (int i = t; i < 2048; i += 256) {
            int r = i >> 4, c = i & 15;
            Whs[r*20 + c] = Wh[i];
        }
        __syncthreads();
    }

    float bv[8], gv[8], bbv[8];
    #pragma unroll
    for (int f = 0; f < 8; f++) {
        bv[f]  = bias[f*16 + l15];
        gv[f]  = lng [f*16 + l15];
        bbv[f] = lnbb[f*16 + l15];
    }
    #pragma unroll
    for (int r2 = 0; r2 < 2; r2++) {
        #pragma unroll
        for (int i = 0; i < 4; i++) {
            int grow = row0 + w*32 + r2*16 + g4*4 + i;
            float vv[8];
            float s = 0.f, sq = 0.f;
            #pragma unroll
            for (int f = 0; f < 8; f++) {
                float av = r2 ? acc1[f][i] : acc0[f][i];
                vv[f] = av + bv[f];
                s  += vv[f];
                sq += vv[f] * vv[f];
            }
            s += __shfl_xor(s, 1);  sq += __shfl_xor(sq, 1);
            s += __shfl_xor(s, 2);  sq += __shfl_xor(sq, 2);
            s += __shfl_xor(s, 4);  sq += __shfl_xor(sq, 4);
            s += __shfl_xor(s, 8);  sq += __shfl_xor(sq, 8);
            float m   = s * (1.f/128.f);
            float var = sq * (1.f/128.f) - m*m;
            float rr  = rsqrtf(var + 1e-5f);
            if (grow < N) {
                if (!FUSE_HEAD) {
                    #pragma unroll
                    for (int f = 0; f < 8; f++) {
                        float y = (vv[f] - m) * rr * gv[f] + bbv[f];
                        y = fmaxf(y, 0.f);
                        out[(size_t)grow*DIM + f*16 + l15] = f2b(y);
                    }
                } else {
                    // rounded-to-bf16 activations (numerics match unfused path)
                    float yr[8];
                    #pragma unroll
                    for (int f = 0; f < 8; f++) {
                        float y = (vv[f] - m) * rr * gv[f] + bbv[f];
                        y = fmaxf(y, 0.f);
                        yr[f] = b2f((uint)f2b(y));
                    }
                    f32x4 p0 = {0,0,0,0}, p1 = {0,0,0,0},
                          p2 = {0,0,0,0}, p3 = {0,0,0,0};
                    #pragma unroll
                    for (int f = 0; f < 8; f++) {
                        const float* wr = Whs + (f*16 + l15)*20;
                        f32x4 w0 = *(const f32x4*)(wr + 0);
                        f32x4 w1 = *(const f32x4*)(wr + 4);
                        f32x4 w2 = *(const f32x4*)(wr + 8);
                        f32x4 w3 = *(const f32x4*)(wr + 12);
                        p0 += yr[f] * w0;
                        p1 += yr[f] * w1;
                        p2 += yr[f] * w2;
                        p3 += yr[f] * w3;
                    }
                    #pragma unroll
                    for (int mskk = 1; mskk <= 8; mskk <<= 1) {
                        #pragma unroll
                        for (int c = 0; c < 4; c++) {
                            p0[c] += __shfl_xor(p0[c], mskk);
                            p1[c] += __shfl_xor(p1[c], mskk);
                            p2[c] += __shfl_xor(p2[c], mskk);
                            p3[c] += __shfl_xor(p3[c], mskk);
                        }
                    }
                    if (l15 == 0) {
                        float* ho = hout + (size_t)grow * NCLS;
                        #pragma unroll
                        for (int c = 0; c < 4; c++) ho[c]      = p0[c] + bh[c];
                        #pragma unroll
                        for (int c = 0; c < 4; c++) ho[4 + c]  = p1[c] + bh[4 + c];
                        #pragma unroll
                        for (int c = 0; c < 4; c++) ho[8 + c]  = p2[c] + bh[8 + c];
                        #pragma unroll
                        for (int c = 0; c < 4; c++) ho[12 + c] = p3[c] + bh[12 + c];
                    }
                }
            }
        }
    }
}

// ---------------------------------------------------------------------------
extern "C" void kernel_launch(void* const* d_in, const int* in_sizes, int n_in,
                              void* d_out, int out_size, void* d_ws, size_t ws_size,
                              hipStream_t stream)
{
    const float* x_paper  = (const float*)d_in[0];
    const float* x_author = (const float*)d_in[1];
    const int*   ei_cites = (const int*)d_in[2];
    const int*   ei_writes= (const int*)d_in[3];
    const int*   ei_rev   = (const int*)d_in[4];
    const float* Wl       = (const float*)d_in[5];
    const float* Wr       = (const float*)d_in[6];
    const float* bl       = (const float*)d_in[7];
    const float* linp     = (const float*)d_in[8];
    const float* lina     = (const float*)d_in[9];
    const float* ln_s     = (const float*)d_in[10];
    const float* ln_b     = (const float*)d_in[11];
    const float* Wh       = (const float*)d_in[12];
    const float* bh       = (const float*)d_in[13];
    float* out = (float*)d_out;

    float* ws = (float*)d_ws;
    size_t off = 0;
    float* Bp     = ws + off; off += 2*384*128;
    float* Ba     = ws + off; off += 2*256*128;
    float* biasp  = ws + off; off += 2*128;
    float* biasa  = ws + off; off += 2*128;
    float* biasp2 = ws + off; off += 2*128;
    float* biasa2 = ws + off; off += 2*128;

    ushort* uws = (ushort*)(ws + off);
    size_t uoff = 0;
    ushort* xpb0 = uws + uoff; uoff += (size_t)NPAPER * DIM;
    ushort* xab0 = uws + uoff; uoff += (size_t)NAUTH  * DIM;
    ushort* xpb1 = uws + uoff; uoff += (size_t)NPAPER * DIM;
    ushort* xab1 = uws + uoff; uoff += (size_t)NAUTH  * DIM;
    ushort* aggC = uws + uoff; uoff += (size_t)NPAPER * DIM;
    ushort* aggW = uws + uoff; uoff += (size_t)NPAPER * DIM;
    ushort* aggR = uws + uoff; uoff += (size_t)NAUTH  * DIM;
    ushort* Btp  = uws + uoff; uoff += 2*49152;
    ushort* Bta  = uws + uoff; uoff += 2*32768;
    if (uoff & 3) uoff += 4 - (uoff & 3);   // 8B-align what follows

    uint2* stage = (uint2*)(uws + uoff);    // 3E uint2 = 12 MB
    int* iws = (int*)(stage + 3*NEDGE);
    size_t ioff = 0;
    int* rowAll      = iws + ioff; ioff += NTOT + 1;
    int* colAll      = iws + ioff; ioff += 3*NEDGE;
    int* bucketCount = iws + ioff; ioff += 256;
    int* emitCursor  = iws + ioff; ioff += 256;   // contiguous with bucketCount

    const int TOBF = (NPAPER + NAUTH) * DIM / 4 / 256;   // 18750

    // L0: bucket_count ∥ prep_weights ∥ to_bf16   (zero bucketCount+emitCursor)
    hipMemsetAsync(bucketCount, 0, 512*4, stream);
    misc0<<<NBLK_A + PREPB + TOBF, 256, 0, stream>>>(
        ei_cites, ei_writes, ei_rev, bucketCount,
        Wl, Wr, bl, Bp, Ba, biasp, biasa,
        x_paper, x_author, xpb0, xab0);
    // L1: fold_bias ∥ build_bt ∥ bucket_emit (scan inlined per block)
    misc1<<<2 + BTB + NBLK_A, 256, 0, stream>>>(
        biasp, biasa, linp, lina, biasp2, biasa2,
        Bp, Ba, Btp, Bta,
        ei_cites, ei_writes, ei_rev,
        bucketCount, emitCursor, stage);
    // L2: CSR finalize (scan inlined)
    csr_fillB<<<NB, 256, 0, stream>>>(stage, bucketCount, rowAll, colAll);

    // ---- layer 0 ----
    gather_seg<<<(size_t)NTOT*16/256, 256, 0, stream>>>(
        0, NTOT, xpb0, xab0, rowAll, colAll, aggC, aggW, aggR);
    gemm_ln2<0><<<PBLK + ABLK, 256, 0, stream>>>(
        aggC, aggW, aggR, xpb0, xab0,
        Btp, Bta, biasp2, biasa2, ln_s, ln_b,
        xpb1, xab1, PBLK, nullptr, nullptr, nullptr);

    // ---- layer 1 (author path dead; head fused into paper GEMM epilogue) ----
    gather_seg<<<(size_t)2*NPAPER*16/256, 256, 0, stream>>>(
        0, 2*NPAPER, xpb1, xab1, rowAll, colAll, aggC, aggW, aggR);
    gemm_ln2<1><<<PBLK, 256, 0, stream>>>(
        aggC, aggW, aggR, xpb1, xab1,
        Btp + 49152, Bta + 32768, biasp2 + 128, biasa2 + 128,
        ln_s + 256, ln_b + 256,
        nullptr, nullptr, PBLK, Wh, bh, out);
}

// Round 16
// 289.845 us; speedup vs baseline: 1.0702x; 1.0431x over previous
//
#include <hip/hip_runtime.h>
#include <math.h>

#define NPAPER 100000
#define NAUTH  50000
#define DIM    128
#define NEDGE  500000
#define NCLS   16
#define NTOT   (2*NPAPER + NAUTH)   // concatenated CSR node space (C | W | R)
#define NB     245                  // buckets of 1024 nodes over NTOT
#define CHUNK_A 11776               // edges per bucketize block
#define NBLK_A  128                 // ceil(3*NEDGE / CHUNK_A)
#define PBLK64 ((NPAPER + 63) / 64)    // 1563 (64-row GEMM tiles)
#define ABLK64 ((NAUTH  + 63) / 64)    // 782

typedef unsigned int   uint;
typedef unsigned short ushort;
typedef unsigned char  uchar;
using short8 = __attribute__((ext_vector_type(8))) short;
using f32x4  = __attribute__((ext_vector_type(4))) float;

__device__ __forceinline__ float b2f(uint u) {
    return __uint_as_float(u << 16);
}
__device__ __forceinline__ ushort f2b(float f) {   // round-to-nearest-even
    uint x = __float_as_uint(f);
    return (ushort)((x + 0x7fffu + ((x >> 16) & 1u)) >> 16);
}

// global_load_lds: linear LDS dest (wave base + lane*16), per-lane global src.
#define GLD_LDS16(srcp, ldsp) \
    __builtin_amdgcn_global_load_lds( \
        (const __attribute__((address_space(1))) void*)(srcp), \
        (__attribute__((address_space(3))) void*)(ldsp), 16, 0, 0)

// ---------------------------------------------------------------------------
// prep bodies (block-indexed device functions, merged into lean misc kernels)
// ---------------------------------------------------------------------------
__device__ __forceinline__ void prep_weights_body(int b, int tid,
    const float* __restrict__ Wl, const float* __restrict__ Wr,
    const float* __restrict__ bl,
    float* __restrict__ Bp, float* __restrict__ Ba,
    float* __restrict__ biasp, float* __restrict__ biasa)
{
    int t = b * 256 + tid;
    if (t < 2*384*128) {
        int l = t / (384*128); int rem = t - l*(384*128);
        int k = rem >> 7, j = rem & 127;
        float v;
        if (k < 128)      v = Wl[((l*3+0)*128 + j)*128 + k];
        else if (k < 256) v = Wl[((l*3+1)*128 + j)*128 + (k-128)];
        else              v = Wr[((l*3+0)*128 + j)*128 + (k-256)]
                            + Wr[((l*3+1)*128 + j)*128 + (k-256)];
        Bp[t] = v;
        return;
    }
    t -= 2*384*128;
    if (t < 2*256*128) {
        int l = t / (256*128); int rem = t - l*(256*128);
        int k = rem >> 7, j = rem & 127;
        Ba[t] = (k < 128) ? Wl[((l*3+2)*128 + j)*128 + k]
                          : Wr[((l*3+2)*128 + j)*128 + (k-128)];
        return;
    }
    t -= 2*256*128;
    if (t < 256) { int l=t>>7, j=t&127; biasp[t] = bl[(l*3+0)*128+j] + bl[(l*3+1)*128+j]; return; }
    t -= 256;
    if (t < 256) { int l=t>>7, j=t&127; biasa[t] = bl[(l*3+2)*128+j]; return; }
}

// residual fold + bf16 + PACK into MFMA-fragment order.
__device__ __forceinline__ size_t pack_off(int j, int k) {
    int kstep = k >> 6, ks = (k >> 5) & 1, g4 = (k >> 3) & 3, jj = k & 7;
    int f = j >> 4, l15 = j & 15;
    return (size_t)kstep*8192 + (size_t)(ks*512 + f*64 + g4*16 + l15)*8 + jj;
}

__device__ __forceinline__ void build_bt_body(int b, int tid,
    const float* __restrict__ Bp, const float* __restrict__ Ba,
    const float* __restrict__ linp, const float* __restrict__ lina,
    ushort* __restrict__ Btp, ushort* __restrict__ Bta)
{
    int t = b * 256 + tid;
    if (t < 2*128*384) {
        int l = t / (128*384); int rem = t - l*(128*384);
        int j = rem / 384, k = rem - j*384;
        const float* brow = Bp + (size_t)l*384*128 + (size_t)k*128;
        float v = brow[j];
        if (l == 0) {
            const float* lrow = linp + (size_t)j*128;
            float s = 0.f;
            #pragma unroll 8
            for (int m = 0; m < 128; m++) s += brow[m] * lrow[m];
            v += s;
        }
        Btp[(size_t)l*49152 + pack_off(j, k)] = f2b(v);
        return;
    }
    t -= 2*128*384;
    if (t < 2*128*256) {
        int l = t / (128*256); int rem = t - l*(128*256);
        int j = rem / 256, k = rem - j*256;
        const float* brow = Ba + (size_t)l*256*128 + (size_t)k*128;
        float v = brow[j];
        if (l == 0) {
            const float* lrow = lina + (size_t)j*128;
            float s = 0.f;
            #pragma unroll 8
            for (int m = 0; m < 128; m++) s += brow[m] * lrow[m];
            v += s;
        }
        Bta[(size_t)l*32768 + pack_off(j, k)] = f2b(v);
    }
}

__device__ __forceinline__ void fold_bias_body(int b, int tid,
    const float* __restrict__ biasp, const float* __restrict__ biasa,
    const float* __restrict__ linp, const float* __restrict__ lina,
    float* __restrict__ biasp2, float* __restrict__ biasa2)
{
    int t = b * 256 + tid;   // 512 total
    int isa = t >> 8; int r = t & 255;
    int l = r >> 7, j = r & 127;
    const float* bsrc = isa ? biasa : biasp;
    const float* lin  = isa ? lina  : linp;
    float v = bsrc[r];
    if (l == 0) {
        float s = 0.f;
        for (int k = 0; k < 128; k++) s += bsrc[k] * lin[j*128 + k];
        v += s;
    }
    (isa ? biasa2 : biasp2)[r] = v;
}

__device__ __forceinline__ void to_bf16_body(int b, int tid,
    const float* __restrict__ xp, const float* __restrict__ xa,
    ushort* __restrict__ yp, ushort* __restrict__ ya)
{
    int i = b * 256 + tid;
    const int n4p = NPAPER * DIM / 4;
    const float* x; ushort* y;
    if (i < n4p) { x = xp; y = yp; }
    else { x = xa; y = ya; i -= n4p; }
    float4 v = ((const float4*)x)[i];
    uint2 o;
    o.x = (uint)f2b(v.x) | ((uint)f2b(v.y) << 16);
    o.y = (uint)f2b(v.z) | ((uint)f2b(v.w) << 16);
    ((uint2*)y)[i] = o;
}

// ---------------------------------------------------------------------------
__device__ __forceinline__ int edge_g(const int* __restrict__ eiC,
                                      const int* __restrict__ eiW,
                                      const int* __restrict__ eiR, int i)
{
    int tpe = (i >= 2*NEDGE) ? 2 : ((i >= NEDGE) ? 1 : 0);
    int e = i - tpe*NEDGE;
    const int* ei = (tpe == 0) ? eiC : ((tpe == 1) ? eiW : eiR);
    int base = (tpe == 0) ? 0 : ((tpe == 1) ? NPAPER : 2*NPAPER);
    return base + ei[NEDGE + e];
}

// misc0: [bucket_count (128) | prep_weights (642) | to_bf16 (18750)]
#define PREPB 642
__global__ __launch_bounds__(256) void misc0(
    const int* __restrict__ eiC, const int* __restrict__ eiW,
    const int* __restrict__ eiR, int* __restrict__ bucketCount,
    const float* __restrict__ Wl, const float* __restrict__ Wr,
    const float* __restrict__ bl,
    float* __restrict__ Bp, float* __restrict__ Ba,
    float* __restrict__ biasp, float* __restrict__ biasa,
    const float* __restrict__ xpf, const float* __restrict__ xaf,
    ushort* __restrict__ xpb, ushort* __restrict__ xab)
{
    __shared__ int h[256];
    int b = blockIdx.x, t = threadIdx.x;
    if (b < NBLK_A) {
        h[t] = 0;
        __syncthreads();
        int start = b * CHUNK_A;
        int n = 3*NEDGE - start; if (n > CHUNK_A) n = CHUNK_A;
        for (int i = t; i < n; i += 256)
            atomicAdd(&h[edge_g(eiC, eiW, eiR, start + i) >> 10], 1);
        __syncthreads();
        if (h[t]) atomicAdd(&bucketCount[t], h[t]);
        return;
    }
    b -= NBLK_A;
    if (b < PREPB) {
        prep_weights_body(b, t, Wl, Wr, bl, Bp, Ba, biasp, biasa);
        return;
    }
    b -= PREPB;
    to_bf16_body(b, t, xpf, xaf, xpb, xab);
}

// misc1: [fold_bias (2) | build_bt (640) | bucket_emit (128)]
#define BTB 640
__global__ __launch_bounds__(256) void misc1(
    const float* __restrict__ biasp, const float* __restrict__ biasa,
    const float* __restrict__ linp, const float* __restrict__ lina,
    float* __restrict__ biasp2, float* __restrict__ biasa2,
    const float* __restrict__ Bp, const float* __restrict__ Ba,
    ushort* __restrict__ Btp, ushort* __restrict__ Bta,
    const int* __restrict__ eiC, const int* __restrict__ eiW,
    const int* __restrict__ eiR,
    const int* __restrict__ bucketCount, int* __restrict__ emitCursor,
    uint2* __restrict__ stage)
{
    int blk = blockIdx.x, t = threadIdx.x;
    if (blk < 2) {
        fold_bias_body(blk, t, biasp, biasa, linp, lina, biasp2, biasa2);
        return;
    }
    blk -= 2;
    if (blk < BTB) {
        build_bt_body(blk, t, Bp, Ba, linp, lina, Btp, Bta);
        return;
    }
    int b = blk - BTB;

    __shared__ uchar  bId [CHUNK_A];
    __shared__ ushort rnk [CHUNK_A];
    __shared__ ushort perm[CHUNK_A];
    __shared__ uchar  posB[CHUNK_A];
    __shared__ int lcnt[256];
    __shared__ int lpre[256];
    __shared__ int bbase[256];
    __shared__ int bbs[256];

    // redundant exclusive scan of bucketCount -> bucket bases
    {
        int v = (t < NB) ? bucketCount[t] : 0;
        bbs[t] = v;
        __syncthreads();
        for (int o = 1; o < 256; o <<= 1) {
            int x = (t >= o) ? bbs[t - o] : 0;
            __syncthreads();
            bbs[t] += x;
            __syncthreads();
        }
        int inc = bbs[t];
        __syncthreads();
        bbs[t] = inc - ((t < NB) ? bucketCount[t] : 0);   // exclusive
        __syncthreads();
    }

    int start = b * CHUNK_A;
    int n = 3*NEDGE - start; if (n > CHUNK_A) n = CHUNK_A;
    lcnt[t] = 0;
    __syncthreads();
    for (int i = t; i < n; i += 256) {
        int bb = edge_g(eiC, eiW, eiR, start + i) >> 10;
        bId[i] = (uchar)bb;
        rnk[i] = (ushort)atomicAdd(&lcnt[bb], 1);
    }
    __syncthreads();
    lpre[t] = lcnt[t];
    __syncthreads();
    for (int o = 1; o < 256; o <<= 1) {
        int x = (t >= o) ? lpre[t - o] : 0;
        __syncthreads();
        lpre[t] += x;
        __syncthreads();
    }
    if (lcnt[t] > 0) bbase[t] = bbs[t] + atomicAdd(&emitCursor[t], lcnt[t]);
    __syncthreads();
    for (int i = t; i < n; i += 256) {
        int bb = bId[i];
        int p = (lpre[bb] - lcnt[bb]) + rnk[i];
        perm[p] = (ushort)i;
        posB[p] = (uchar)bb;
    }
    __syncthreads();
    for (int p = t; p < n; p += 256) {
        int bb = posB[p];
        int i = start + perm[p];
        int tpe = (i >= 2*NEDGE) ? 2 : ((i >= NEDGE) ? 1 : 0);
        int e = i - tpe*NEDGE;
        const int* ei = (tpe == 0) ? eiC : ((tpe == 1) ? eiW : eiR);
        int base = (tpe == 0) ? 0 : ((tpe == 1) ? NPAPER : 2*NPAPER);
        uint2 o2;
        o2.x = (uint)(base + ei[NEDGE + e]);
        o2.y = (uint)ei[e];
        stage[bbase[bb] + (p - (lpre[bb] - lcnt[bb]))] = o2;
    }
}

// Per-bucket CSR finalize; bucket bases scanned inline from bucketCount.
__global__ __launch_bounds__(256) void csr_fillB(
    const uint2* __restrict__ stage, const int* __restrict__ bucketCount,
    int* __restrict__ rowAll, int* __restrict__ colAll)
{
    __shared__ int cnt[1024];
    __shared__ int part[256];
    __shared__ int bbs[256];
    int b = blockIdx.x;
    int t = threadIdx.x;

    // inline exclusive scan of bucketCount
    {
        int v = (t < NB) ? bucketCount[t] : 0;
        bbs[t] = v;
        __syncthreads();
        for (int o = 1; o < 256; o <<= 1) {
            int x = (t >= o) ? bbs[t - o] : 0;
            __syncthreads();
            bbs[t] += x;
            __syncthreads();
        }
        int inc = bbs[t];
        __syncthreads();
        bbs[t] = inc - ((t < NB) ? bucketCount[t] : 0);
        __syncthreads();
    }
    int g0 = b << 10;
    int nn = NTOT - g0; if (nn > 1024) nn = 1024;
    int s = bbs[b];
    int e = s + bucketCount[b];

    #pragma unroll
    for (int i = t; i < 1024; i += 256) cnt[i] = 0;
    __syncthreads();
    for (int i = s + t; i < e; i += 256) atomicAdd(&cnt[(int)stage[i].x - g0], 1);
    __syncthreads();
    int loc[4]; int ss = 0;
    #pragma unroll
    for (int j = 0; j < 4; j++) { loc[j] = cnt[t*4 + j]; ss += loc[j]; }
    part[t] = ss;
    __syncthreads();
    for (int o = 1; o < 256; o <<= 1) {
        int x = (t >= o) ? part[t - o] : 0;
        __syncthreads();
        part[t] += x;
        __syncthreads();
    }
    int run = (t > 0) ? part[t-1] : 0;
    #pragma unroll
    for (int j = 0; j < 4; j++) { int c = loc[j]; cnt[t*4 + j] = run; run += c; }
    __syncthreads();
    for (int i = t; i < nn; i += 256) rowAll[g0 + i] = s + cnt[i];
    if (b == NB-1 && t == 0) rowAll[NTOT] = 3*NEDGE;
    __syncthreads();
    for (int i = s + t; i < e; i += 256) {
        uint2 ed = stage[i];
        int slot = atomicAdd(&cnt[(int)ed.x - g0], 1);
        colAll[s + slot] = (int)ed.y;
    }
}

// ---------------------------------------------------------------------------
// Gather-mean (proven round-10 shape): 16 lanes/node, uint4 (16B) row chunks,
// 4-deep load pipeline, dual accumulators -> 16 outstanding row-loads/wave.
__device__ __forceinline__ void acc8(float* a, uint4 v) {
    a[0] += b2f(v.x & 0xffffu); a[1] += b2f(v.x >> 16);
    a[2] += b2f(v.y & 0xffffu); a[3] += b2f(v.y >> 16);
    a[4] += b2f(v.z & 0xffffu); a[5] += b2f(v.z >> 16);
    a[6] += b2f(v.w & 0xffffu); a[7] += b2f(v.w >> 16);
}

__global__ __launch_bounds__(256) void gather_seg(
    int g0, int g1,
    const ushort* __restrict__ xp, const ushort* __restrict__ xa,
    const int* __restrict__ rowAll, const int* __restrict__ colAll,
    ushort* __restrict__ aggC, ushort* __restrict__ aggW,
    ushort* __restrict__ aggR)
{
    int idx = blockIdx.x * 256 + threadIdx.x;
    int g = g0 + (idx >> 4);
    int lane = idx & 15;
    if (g >= g1) return;
    const ushort* xs; ushort* out; int node;
    if (g < NPAPER)        { node = g;            xs = xp; out = aggC; }
    else if (g < 2*NPAPER) { node = g - NPAPER;   xs = xa; out = aggW; }
    else                   { node = g - 2*NPAPER; xs = xp; out = aggR; }

    int s = rowAll[g], e = rowAll[g + 1];
    float a[8] = {0,0,0,0,0,0,0,0};
    float b[8] = {0,0,0,0,0,0,0,0};
    int j = s;
    #pragma unroll 1
    for (; j + 4 <= e; j += 4) {
        int s0 = colAll[j], s1 = colAll[j+1], s2 = colAll[j+2], s3 = colAll[j+3];
        uint4 v0 = *(const uint4*)(xs + (size_t)s0 * DIM + lane * 8);
        uint4 v1 = *(const uint4*)(xs + (size_t)s1 * DIM + lane * 8);
        uint4 v2 = *(const uint4*)(xs + (size_t)s2 * DIM + lane * 8);
        uint4 v3 = *(const uint4*)(xs + (size_t)s3 * DIM + lane * 8);
        acc8(a, v0);
        acc8(b, v1);
        acc8(a, v2);
        acc8(b, v3);
    }
    #pragma unroll 1
    for (; j < e; j++) {
        uint4 v0 = *(const uint4*)(xs + (size_t)colAll[j] * DIM + lane * 8);
        acc8(a, v0);
    }
    float inv = (e > s) ? 1.f / (float)(e - s) : 0.f;
    #pragma unroll
    for (int i = 0; i < 8; i++) a[i] = (a[i] + b[i]) * inv;
    uint4 o;
    o.x = (uint)f2b(a[0]) | ((uint)f2b(a[1]) << 16);
    o.y = (uint)f2b(a[2]) | ((uint)f2b(a[3]) << 16);
    o.z = (uint)f2b(a[4]) | ((uint)f2b(a[5]) << 16);
    o.w = (uint)f2b(a[6]) | ((uint)f2b(a[7]) << 16);
    *(uint4*)(out + (size_t)node * DIM + lane * 8) = o;
}

// ---------------------------------------------------------------------------
// Merged MFMA GEMM + bias + LayerNorm + ReLU, 64-ROW tiles (wave owns 16 rows,
// single acc[8] set -> low VGPR, 2x blocks for latency hiding).
// Blocks [0,pblk): paper rows (K=384, segs aggC|aggW|self-p); [pblk,..):
// author (K=256, segs aggR|self-a).  LDS: As 8 KB ([ks2][rb4][lane64][8]) +
// Bs 16 KB.  FUSE_HEAD=1: head epilogue, Wh staged into Bs (stride-20).
template<int FUSE_HEAD>
__global__ __launch_bounds__(256) void gemm_ln2(
    const ushort* __restrict__ aggC, const ushort* __restrict__ aggW,
    const ushort* __restrict__ aggR,
    const ushort* __restrict__ xp, const ushort* __restrict__ xa,
    const ushort* __restrict__ Btp, const ushort* __restrict__ Bta,
    const float* __restrict__ biasp, const float* __restrict__ biasa,
    const float* __restrict__ lns, const float* __restrict__ lnb,
    ushort* __restrict__ outp, ushort* __restrict__ outa, int pblk,
    const float* __restrict__ Wh, const float* __restrict__ bh,
    float* __restrict__ hout)
{
    __shared__ ushort As[4096];   // 8 KB, one K-step, 64 rows
    __shared__ ushort Bs[8192];   // 16 KB

    bool isp = (int)blockIdx.x < pblk;
    int  bid = isp ? blockIdx.x : (blockIdx.x - pblk);
    int  N   = isp ? NPAPER : NAUTH;
    int  K   = isp ? 384 : 256;
    const ushort* A0 = isp ? aggC : aggR;
    const ushort* A1 = isp ? aggW : xa;
    const ushort* A2 = isp ? xp   : xa;
    const ushort* Bt = isp ? Btp  : Bta;
    const float* bias = isp ? biasp : biasa;
    const float* lng  = lns + (isp ? 0 : 128);
    const float* lnbb = lnb + (isp ? 0 : 128);
    ushort* out = isp ? outp : outa;

    int t    = threadIdx.x;
    int w    = t >> 6;            // 0..3, wave owns rows w*16..w*16+15
    int lane = t & 63;
    int row0 = bid * 64;
    int l15  = lane & 15;
    int g4   = lane >> 4;

    f32x4 acc[8];
    #pragma unroll
    for (int f = 0; f < 8; f++) acc[f] = (f32x4){0.f, 0.f, 0.f, 0.f};

    int nstep = K >> 6;
    for (int st = 0; st < nstep; st++) {
        int kk  = st << 6;
        int seg = kk >> 7, kl = kk & 127;
        const ushort* Ap = (seg == 0) ? A0 : ((seg == 1) ? A1 : A2);

        // stage A: 512 chunks of 16B in [ks(2)][rb(4)][lane(64)] order.
        #pragma unroll
        for (int p = 0; p < 2; p++) {
            int q  = p*256 + t;
            int ks = q >> 8, rb = (q >> 6) & 3, l = q & 63;
            int row = row0 + rb*16 + (l & 15);
            row = (row < N) ? row : (N - 1);
            int k = kl + ks*32 + (l >> 4)*8;
            int qbase = p*256 + w*64;
            GLD_LDS16(Ap + (size_t)row*DIM + k, As + qbase*8);
        }
        // stage B: linear copy of 16 KB from packed Bt.
        #pragma unroll
        for (int p = 0; p < 4; p++) {
            int q = p*256 + t;
            int qbase = p*256 + w*64;
            GLD_LDS16(Bt + ((size_t)st*8192 + (size_t)q*8), Bs + qbase*8);
        }
        __syncthreads();

        #pragma unroll
        for (int ks = 0; ks < 2; ks++) {
            short8 a0 = *(const short8*)(&As[((ks*4 + w)*64 + lane)*8]);
            #pragma unroll
            for (int f = 0; f < 8; f++) {
                short8 bv = *(const short8*)(&Bs[((ks*8 + f)*64 + lane)*8]);
                acc[f] = __builtin_amdgcn_mfma_f32_16x16x32_bf16(a0, bv, acc[f], 0, 0, 0);
            }
        }
        __syncthreads();
    }

    float* Whs = (float*)Bs;   // 128 x 20 floats = 10.25 KB <= 16 KB
    if (FUSE_HEAD) {
        for (int i = t; i < 2048; i += 256) {
            int r = i >> 4, c = i & 15;
            Whs[r*20 + c] = Wh[i];
        }
        __syncthreads();
    }

    float bv[8], gv[8], bbv[8];
    #pragma unroll
    for (int f = 0; f < 8; f++) {
        bv[f]  = bias[f*16 + l15];
        gv[f]  = lng [f*16 + l15];
        bbv[f] = lnbb[f*16 + l15];
    }
    #pragma unroll
    for (int i = 0; i < 4; i++) {
        int grow = row0 + w*16 + g4*4 + i;
        float vv[8];
        float s = 0.f, sq = 0.f;
        #pragma unroll
        for (int f = 0; f < 8; f++) {
            vv[f] = acc[f][i] + bv[f];
            s  += vv[f];
            sq += vv[f] * vv[f];
        }
        s += __shfl_xor(s, 1);  sq += __shfl_xor(sq, 1);
        s += __shfl_xor(s, 2);  sq += __shfl_xor(sq, 2);
        s += __shfl_xor(s, 4);  sq += __shfl_xor(sq, 4);
        s += __shfl_xor(s, 8);  sq += __shfl_xor(sq, 8);
        float m   = s * (1.f/128.f);
        float var = sq * (1.f/128.f) - m*m;
        float rr  = rsqrtf(var + 1e-5f);
        if (grow < N) {
            if (!FUSE_HEAD) {
                #pragma unroll
                for (int f = 0; f < 8; f++) {
                    float y = (vv[f] - m) * rr * gv[f] + bbv[f];
                    y = fmaxf(y, 0.f);
                    out[(size_t)grow*DIM + f*16 + l15] = f2b(y);
                }
            } else {
                float yr[8];
                #pragma unroll
                for (int f = 0; f < 8; f++) {
                    float y = (vv[f] - m) * rr * gv[f] + bbv[f];
                    y = fmaxf(y, 0.f);
                    yr[f] = b2f((uint)f2b(y));
                }
                f32x4 p0 = {0,0,0,0}, p1 = {0,0,0,0},
                      p2 = {0,0,0,0}, p3 = {0,0,0,0};
                #pragma unroll
                for (int f = 0; f < 8; f++) {
                    const float* wr = Whs + (f*16 + l15)*20;
                    p0 += yr[f] * *(const f32x4*)(wr + 0);
                    p1 += yr[f] * *(const f32x4*)(wr + 4);
                    p2 += yr[f] * *(const f32x4*)(wr + 8);
                    p3 += yr[f] * *(const f32x4*)(wr + 12);
                }
                #pragma unroll
                for (int mskk = 1; mskk <= 8; mskk <<= 1) {
                    #pragma unroll
                    for (int c = 0; c < 4; c++) {
                        p0[c] += __shfl_xor(p0[c], mskk);
                        p1[c] += __shfl_xor(p1[c], mskk);
                        p2[c] += __shfl_xor(p2[c], mskk);
                        p3[c] += __shfl_xor(p3[c], mskk);
                    }
                }
                if (l15 == 0) {
                    float* ho = hout + (size_t)grow * NCLS;
                    #pragma unroll
                    for (int c = 0; c < 4; c++) ho[c]      = p0[c] + bh[c];
                    #pragma unroll
                    for (int c = 0; c < 4; c++) ho[4 + c]  = p1[c] + bh[4 + c];
                    #pragma unroll
                    for (int c = 0; c < 4; c++) ho[8 + c]  = p2[c] + bh[8 + c];
                    #pragma unroll
                    for (int c = 0; c < 4; c++) ho[12 + c] = p3[c] + bh[12 + c];
                }
            }
        }
    }
}

// ---------------------------------------------------------------------------
extern "C" void kernel_launch(void* const* d_in, const int* in_sizes, int n_in,
                              void* d_out, int out_size, void* d_ws, size_t ws_size,
                              hipStream_t stream)
{
    const float* x_paper  = (const float*)d_in[0];
    const float* x_author = (const float*)d_in[1];
    const int*   ei_cites = (const int*)d_in[2];
    const int*   ei_writes= (const int*)d_in[3];
    const int*   ei_rev   = (const int*)d_in[4];
    const float* Wl       = (const float*)d_in[5];
    const float* Wr       = (const float*)d_in[6];
    const float* bl       = (const float*)d_in[7];
    const float* linp     = (const float*)d_in[8];
    const float* lina     = (const float*)d_in[9];
    const float* ln_s     = (const float*)d_in[10];
    const float* ln_b     = (const float*)d_in[11];
    const float* Wh       = (const float*)d_in[12];
    const float* bh       = (const float*)d_in[13];
    float* out = (float*)d_out;

    float* ws = (float*)d_ws;
    size_t off = 0;
    float* Bp     = ws + off; off += 2*384*128;
    float* Ba     = ws + off; off += 2*256*128;
    float* biasp  = ws + off; off += 2*128;
    float* biasa  = ws + off; off += 2*128;
    float* biasp2 = ws + off; off += 2*128;
    float* biasa2 = ws + off; off += 2*128;

    ushort* uws = (ushort*)(ws + off);
    size_t uoff = 0;
    ushort* xpb0 = uws + uoff; uoff += (size_t)NPAPER * DIM;
    ushort* xab0 = uws + uoff; uoff += (size_t)NAUTH  * DIM;
    ushort* xpb1 = uws + uoff; uoff += (size_t)NPAPER * DIM;
    ushort* xab1 = uws + uoff; uoff += (size_t)NAUTH  * DIM;
    ushort* aggC = uws + uoff; uoff += (size_t)NPAPER * DIM;
    ushort* aggW = uws + uoff; uoff += (size_t)NPAPER * DIM;
    ushort* aggR = uws + uoff; uoff += (size_t)NAUTH  * DIM;
    ushort* Btp  = uws + uoff; uoff += 2*49152;
    ushort* Bta  = uws + uoff; uoff += 2*32768;
    if (uoff & 3) uoff += 4 - (uoff & 3);   // 8B-align what follows

    uint2* stage = (uint2*)(uws + uoff);    // 3E uint2 = 12 MB
    int* iws = (int*)(stage + 3*NEDGE);
    size_t ioff = 0;
    int* rowAll      = iws + ioff; ioff += NTOT + 1;
    int* colAll      = iws + ioff; ioff += 3*NEDGE;
    int* bucketCount = iws + ioff; ioff += 256;
    int* emitCursor  = iws + ioff; ioff += 256;   // contiguous with bucketCount

    const int TOBF = (NPAPER + NAUTH) * DIM / 4 / 256;   // 18750

    // L0: bucket_count ∥ prep_weights ∥ to_bf16   (zero bucketCount+emitCursor)
    hipMemsetAsync(bucketCount, 0, 512*4, stream);
    misc0<<<NBLK_A + PREPB + TOBF, 256, 0, stream>>>(
        ei_cites, ei_writes, ei_rev, bucketCount,
        Wl, Wr, bl, Bp, Ba, biasp, biasa,
        x_paper, x_author, xpb0, xab0);
    // L1: fold_bias ∥ build_bt ∥ bucket_emit (scan inlined per block)
    misc1<<<2 + BTB + NBLK_A, 256, 0, stream>>>(
        biasp, biasa, linp, lina, biasp2, biasa2,
        Bp, Ba, Btp, Bta,
        ei_cites, ei_writes, ei_rev,
        bucketCount, emitCursor, stage);
    // L2: CSR finalize (scan inlined)
    csr_fillB<<<NB, 256, 0, stream>>>(stage, bucketCount, rowAll, colAll);

    // ---- layer 0 ----
    gather_seg<<<(size_t)NTOT*16/256, 256, 0, stream>>>(
        0, NTOT, xpb0, xab0, rowAll, colAll, aggC, aggW, aggR);
    gemm_ln2<0><<<PBLK64 + ABLK64, 256, 0, stream>>>(
        aggC, aggW, aggR, xpb0, xab0,
        Btp, Bta, biasp2, biasa2, ln_s, ln_b,
        xpb1, xab1, PBLK64, nullptr, nullptr, nullptr);

    // ---- layer 1 (author path dead; head fused into paper GEMM epilogue) ----
    gather_seg<<<(size_t)2*NPAPER*16/256, 256, 0, stream>>>(
        0, 2*NPAPER, xpb1, xab1, rowAll, colAll, aggC, aggW, aggR);
    gemm_ln2<1><<<PBLK64, 256, 0, stream>>>(
        aggC, aggW, aggR, xpb1, xab1,
        Btp + 49152, Bta + 32768, biasp2 + 128, biasa2 + 128,
        ln_s + 256, ln_b + 256,
        nullptr, nullptr, PBLK64, Wh, bh, out);
}

// Round 17
// 257.982 us; speedup vs baseline: 1.2023x; 1.1235x over previous
//
#include <hip/hip_runtime.h>
#include <math.h>

#define NPAPER 100000
#define NAUTH  50000
#define DIM    128
#define NEDGE  500000
#define NCLS   16
#define NTOT   (2*NPAPER + NAUTH)   // concatenated CSR node space (C | W | R)
#define NB     245                  // buckets of 1024 nodes over NTOT
#define BCAP   12288                // fixed per-bucket capacity (R-mean 10240 + 20 sigma)
#define CHUNK_E 5888                // edges per emit block
#define NBLK_E  256                 // 256*5888 >= 3*NEDGE
#define PBLK64 ((NPAPER + 63) / 64)    // 1563 (64-row GEMM tiles)
#define ABLK64 ((NAUTH  + 63) / 64)    // 782

typedef unsigned int   uint;
typedef unsigned short ushort;
typedef unsigned char  uchar;
using short8 = __attribute__((ext_vector_type(8))) short;
using f32x4  = __attribute__((ext_vector_type(4))) float;

__device__ __forceinline__ float b2f(uint u) {
    return __uint_as_float(u << 16);
}
__device__ __forceinline__ ushort f2b(float f) {   // round-to-nearest-even
    uint x = __float_as_uint(f);
    return (ushort)((x + 0x7fffu + ((x >> 16) & 1u)) >> 16);
}

// global_load_lds: linear LDS dest (wave base + lane*16), per-lane global src.
#define GLD_LDS16(srcp, ldsp) \
    __builtin_amdgcn_global_load_lds( \
        (const __attribute__((address_space(1))) void*)(srcp), \
        (__attribute__((address_space(3))) void*)(ldsp), 16, 0, 0)

// ---------------------------------------------------------------------------
__device__ __forceinline__ int edge_g(const int* __restrict__ eiC,
                                      const int* __restrict__ eiW,
                                      const int* __restrict__ eiR, int i)
{
    int tpe = (i >= 2*NEDGE) ? 2 : ((i >= NEDGE) ? 1 : 0);
    int e = i - tpe*NEDGE;
    const int* ei = (tpe == 0) ? eiC : ((tpe == 1) ? eiW : eiR);
    int base = (tpe == 0) ? 0 : ((tpe == 1) ? NPAPER : 2*NPAPER);
    return base + ei[NEDGE + e];
}

// ---------------------------------------------------------------------------
// Kernel 1: bucket emit with fixed-capacity buckets (no count pass, no scan).
// Per-block LDS rank/permute -> position-sorted bursty writes into
// stage[bucket*BCAP + cursor-allocated range].  Depends only on edge lists.
__global__ __launch_bounds__(256) void bucket_emit(
    const int* __restrict__ eiC, const int* __restrict__ eiW,
    const int* __restrict__ eiR,
    int* __restrict__ cursor, uint2* __restrict__ stage)
{
    __shared__ uchar  bId [CHUNK_E];
    __shared__ ushort rnk [CHUNK_E];
    __shared__ ushort perm[CHUNK_E];
    __shared__ uchar  posB[CHUNK_E];
    __shared__ int lcnt[256];
    __shared__ int lpre[256];
    __shared__ int bbase[256];

    int b = blockIdx.x, t = threadIdx.x;
    int start = b * CHUNK_E;
    int n = 3*NEDGE - start;
    if (n > CHUNK_E) n = CHUNK_E;
    if (n < 0) n = 0;
    lcnt[t] = 0;
    __syncthreads();
    for (int i = t; i < n; i += 256) {
        int bb = edge_g(eiC, eiW, eiR, start + i) >> 10;
        bId[i] = (uchar)bb;
        rnk[i] = (ushort)atomicAdd(&lcnt[bb], 1);
    }
    __syncthreads();
    lpre[t] = lcnt[t];
    __syncthreads();
    for (int o = 1; o < 256; o <<= 1) {
        int x = (t >= o) ? lpre[t - o] : 0;
        __syncthreads();
        lpre[t] += x;
        __syncthreads();
    }
    if (lcnt[t] > 0) bbase[t] = t*BCAP + atomicAdd(&cursor[t], lcnt[t]);
    __syncthreads();
    for (int i = t; i < n; i += 256) {
        int bb = bId[i];
        int p = (lpre[bb] - lcnt[bb]) + rnk[i];
        perm[p] = (ushort)i;
        posB[p] = (uchar)bb;
    }
    __syncthreads();
    for (int p = t; p < n; p += 256) {
        int bb = posB[p];
        int i = start + perm[p];
        int tpe = (i >= 2*NEDGE) ? 2 : ((i >= NEDGE) ? 1 : 0);
        int e = i - tpe*NEDGE;
        const int* ei = (tpe == 0) ? eiC : ((tpe == 1) ? eiW : eiR);
        int base = (tpe == 0) ? 0 : ((tpe == 1) ? NPAPER : 2*NPAPER);
        uint2 o2;
        o2.x = (uint)(base + ei[NEDGE + e]);
        o2.y = (uint)ei[e];
        stage[bbase[bb] + (p - (lpre[bb] - lcnt[bb]))] = o2;
    }
}

// ---------------------------------------------------------------------------
// misc1 bodies (lean, run alongside fillB in one launch)
// ---------------------------------------------------------------------------
// fp32 -> bf16 for both inputs; 4 elems/thread.
__device__ __forceinline__ void to_bf16_body(int b, int tid,
    const float* __restrict__ xp, const float* __restrict__ xa,
    ushort* __restrict__ yp, ushort* __restrict__ ya)
{
    int i = b * 256 + tid;
    const int n4p = NPAPER * DIM / 4;
    const float* x; ushort* y;
    if (i < n4p) { x = xp; y = yp; }
    else { x = xa; y = ya; i -= n4p; }
    float4 v = ((const float4*)x)[i];
    uint2 o;
    o.x = (uint)f2b(v.x) | ((uint)f2b(v.y) << 16);
    o.y = (uint)f2b(v.z) | ((uint)f2b(v.w) << 16);
    ((uint2*)y)[i] = o;
}

// residual fold + bf16 + PACK into MFMA-fragment order, DIRECT from Wl/Wr.
// Btp[l][j][k] = W~[j][kk] + (l==0 ? sum_m W~[m][kk]*linp[j][m] : 0)
// where W~ = Wl[l,seg] (seg<2) or Wr[l,0]+Wr[l,1] (seg 2); author analog.
__device__ __forceinline__ size_t pack_off(int j, int k) {
    int kstep = k >> 6, ks = (k >> 5) & 1, g4 = (k >> 3) & 3, jj = k & 7;
    int f = j >> 4, l15 = j & 15;
    return (size_t)kstep*8192 + (size_t)(ks*512 + f*64 + g4*16 + l15)*8 + jj;
}

__device__ __forceinline__ void build_bt2_body(int b, int tid,
    const float* __restrict__ Wl, const float* __restrict__ Wr,
    const float* __restrict__ linp, const float* __restrict__ lina,
    ushort* __restrict__ Btp, ushort* __restrict__ Bta)
{
    int t = b * 256 + tid;
    if (t < 2*128*384) {
        int l = t / (128*384); int rem = t - l*(128*384);
        int j = rem / 384, k = rem - j*384;
        int seg = k >> 7, kk = k & 127;
        float v, s = 0.f;
        if (seg < 2) {
            const float* W = Wl + (size_t)((l*3 + seg)*128)*128;
            v = W[j*128 + kk];
            if (l == 0) {
                const float* lrow = linp + (size_t)j*128;
                #pragma unroll 8
                for (int m = 0; m < 128; m++) s += W[m*128 + kk] * lrow[m];
            }
        } else {
            const float* W0 = Wr + (size_t)((l*3 + 0)*128)*128;
            const float* W1 = Wr + (size_t)((l*3 + 1)*128)*128;
            v = W0[j*128 + kk] + W1[j*128 + kk];
            if (l == 0) {
                const float* lrow = linp + (size_t)j*128;
                #pragma unroll 8
                for (int m = 0; m < 128; m++)
                    s += (W0[m*128 + kk] + W1[m*128 + kk]) * lrow[m];
            }
        }
        Btp[(size_t)l*49152 + pack_off(j, k)] = f2b(v + s);
        return;
    }
    t -= 2*128*384;
    if (t < 2*128*256) {
        int l = t / (128*256); int rem = t - l*(128*256);
        int j = rem / 256, k = rem - j*256;
        int seg = k >> 7, kk = k & 127;
        const float* W = (seg == 0) ? (Wl + (size_t)((l*3 + 2)*128)*128)
                                    : (Wr + (size_t)((l*3 + 2)*128)*128);
        float v = W[j*128 + kk], s = 0.f;
        if (l == 0) {
            const float* lrow = lina + (size_t)j*128;
            #pragma unroll 8
            for (int m = 0; m < 128; m++) s += W[m*128 + kk] * lrow[m];
        }
        Bta[(size_t)l*32768 + pack_off(j, k)] = f2b(v + s);
    }
}

// bias direct from bl: biasp = bl[l,0]+bl[l,1] (paper) / bl[l,2] (author),
// then folded through (I + lin^T) for l==0.
__device__ __forceinline__ void fold_bias2_body(int b, int tid,
    const float* __restrict__ bl,
    const float* __restrict__ linp, const float* __restrict__ lina,
    float* __restrict__ biasp2, float* __restrict__ biasa2)
{
    int t = b * 256 + tid;   // 512 total
    int isa = t >> 8; int r = t & 255;
    int l = r >> 7, j = r & 127;
    float v;
    if (!isa) {
        v = bl[(l*3+0)*128 + j] + bl[(l*3+1)*128 + j];
        if (l == 0) {
            float s = 0.f;
            for (int k = 0; k < 128; k++)
                s += (bl[k] + bl[128 + k]) * linp[j*128 + k];
            v += s;
        }
        biasp2[r] = v;
    } else {
        v = bl[(l*3+2)*128 + j];
        if (l == 0) {
            float s = 0.f;
            for (int k = 0; k < 128; k++)
                s += bl[2*128 + k] * lina[j*128 + k];
            v += s;
        }
        biasa2[r] = v;
    }
}

// fillB body: per-bucket CSR finalize with fixed base b*BCAP.
// rowse[g] = (start, end) global offsets into colAll.
__device__ void fillB_body(int b, int t,
    const uint2* __restrict__ stage, const int* __restrict__ cursor,
    uint2* __restrict__ rowse, int* __restrict__ colAll)
{
    __shared__ int cnt[1024];
    __shared__ int part[256];
    int g0 = b << 10;
    int nn = NTOT - g0; if (nn > 1024) nn = 1024;
    int base = b * BCAP;
    int cntE = cursor[b];

    #pragma unroll
    for (int i = t; i < 1024; i += 256) cnt[i] = 0;
    __syncthreads();
    for (int i = t; i < cntE; i += 256)
        atomicAdd(&cnt[(int)stage[base + i].x - g0], 1);
    __syncthreads();
    int loc[4]; int ss = 0;
    #pragma unroll
    for (int j = 0; j < 4; j++) { loc[j] = cnt[t*4 + j]; ss += loc[j]; }
    part[t] = ss;
    __syncthreads();
    for (int o = 1; o < 256; o <<= 1) {
        int x = (t >= o) ? part[t - o] : 0;
        __syncthreads();
        part[t] += x;
        __syncthreads();
    }
    int run = (t > 0) ? part[t-1] : 0;
    #pragma unroll
    for (int j = 0; j < 4; j++) {
        int node = g0 + t*4 + j;
        if (t*4 + j < nn) {
            uint2 se;
            se.x = (uint)(base + run);
            se.y = (uint)(base + run + loc[j]);
            rowse[node] = se;
        }
        cnt[t*4 + j] = run;
        run += loc[j];
    }
    __syncthreads();
    for (int i = t; i < cntE; i += 256) {
        uint2 ed = stage[base + i];
        int slot = atomicAdd(&cnt[(int)ed.x - g0], 1);
        colAll[base + slot] = (int)ed.y;
    }
}

// Kernel 2: [fillB (NB) | to_bf16 (TOBF) | build_bt2 (BTB) | fold_bias2 (2)]
#define BTB  640
#define TOBF ((NPAPER + NAUTH) * DIM / 4 / 256)   // 18750
__global__ __launch_bounds__(256) void misc1(
    const uint2* __restrict__ stage, const int* __restrict__ cursor,
    uint2* __restrict__ rowse, int* __restrict__ colAll,
    const float* __restrict__ xpf, const float* __restrict__ xaf,
    ushort* __restrict__ xpb, ushort* __restrict__ xab,
    const float* __restrict__ Wl, const float* __restrict__ Wr,
    const float* __restrict__ bl,
    const float* __restrict__ linp, const float* __restrict__ lina,
    ushort* __restrict__ Btp, ushort* __restrict__ Bta,
    float* __restrict__ biasp2, float* __restrict__ biasa2)
{
    int blk = blockIdx.x, t = threadIdx.x;
    if (blk < NB) { fillB_body(blk, t, stage, cursor, rowse, colAll); return; }
    blk -= NB;
    if (blk < TOBF) { to_bf16_body(blk, t, xpf, xaf, xpb, xab); return; }
    blk -= TOBF;
    if (blk < BTB) { build_bt2_body(blk, t, Wl, Wr, linp, lina, Btp, Bta); return; }
    blk -= BTB;
    fold_bias2_body(blk, t, bl, linp, lina, biasp2, biasa2);
}

// ---------------------------------------------------------------------------
// Gather-mean (proven shape): 16 lanes/node, uint4 (16B) row chunks,
// 4-deep load pipeline, dual accumulators -> 16 outstanding row-loads/wave.
__device__ __forceinline__ void acc8(float* a, uint4 v) {
    a[0] += b2f(v.x & 0xffffu); a[1] += b2f(v.x >> 16);
    a[2] += b2f(v.y & 0xffffu); a[3] += b2f(v.y >> 16);
    a[4] += b2f(v.z & 0xffffu); a[5] += b2f(v.z >> 16);
    a[6] += b2f(v.w & 0xffffu); a[7] += b2f(v.w >> 16);
}

__global__ __launch_bounds__(256) void gather_seg(
    int g0, int g1,
    const ushort* __restrict__ xp, const ushort* __restrict__ xa,
    const uint2* __restrict__ rowse, const int* __restrict__ colAll,
    ushort* __restrict__ aggC, ushort* __restrict__ aggW,
    ushort* __restrict__ aggR)
{
    int idx = blockIdx.x * 256 + threadIdx.x;
    int g = g0 + (idx >> 4);
    int lane = idx & 15;
    if (g >= g1) return;
    const ushort* xs; ushort* out; int node;
    if (g < NPAPER)        { node = g;            xs = xp; out = aggC; }
    else if (g < 2*NPAPER) { node = g - NPAPER;   xs = xa; out = aggW; }
    else                   { node = g - 2*NPAPER; xs = xp; out = aggR; }

    uint2 se = rowse[g];
    int s = (int)se.x, e = (int)se.y;
    float a[8] = {0,0,0,0,0,0,0,0};
    float b[8] = {0,0,0,0,0,0,0,0};
    int j = s;
    #pragma unroll 1
    for (; j + 4 <= e; j += 4) {
        int s0 = colAll[j], s1 = colAll[j+1], s2 = colAll[j+2], s3 = colAll[j+3];
        uint4 v0 = *(const uint4*)(xs + (size_t)s0 * DIM + lane * 8);
        uint4 v1 = *(const uint4*)(xs + (size_t)s1 * DIM + lane * 8);
        uint4 v2 = *(const uint4*)(xs + (size_t)s2 * DIM + lane * 8);
        uint4 v3 = *(const uint4*)(xs + (size_t)s3 * DIM + lane * 8);
        acc8(a, v0);
        acc8(b, v1);
        acc8(a, v2);
        acc8(b, v3);
    }
    #pragma unroll 1
    for (; j < e; j++) {
        uint4 v0 = *(const uint4*)(xs + (size_t)colAll[j] * DIM + lane * 8);
        acc8(a, v0);
    }
    float inv = (e > s) ? 1.f / (float)(e - s) : 0.f;
    #pragma unroll
    for (int i = 0; i < 8; i++) a[i] = (a[i] + b[i]) * inv;
    uint4 o;
    o.x = (uint)f2b(a[0]) | ((uint)f2b(a[1]) << 16);
    o.y = (uint)f2b(a[2]) | ((uint)f2b(a[3]) << 16);
    o.z = (uint)f2b(a[4]) | ((uint)f2b(a[5]) << 16);
    o.w = (uint)f2b(a[6]) | ((uint)f2b(a[7]) << 16);
    *(uint4*)(out + (size_t)node * DIM + lane * 8) = o;
}

// ---------------------------------------------------------------------------
// Merged MFMA GEMM + bias + LayerNorm + ReLU, 64-ROW tiles (proven round-16).
// FUSE_HEAD=1: head epilogue, Wh staged into Bs (stride-20).
template<int FUSE_HEAD>
__global__ __launch_bounds__(256) void gemm_ln2(
    const ushort* __restrict__ aggC, const ushort* __restrict__ aggW,
    const ushort* __restrict__ aggR,
    const ushort* __restrict__ xp, const ushort* __restrict__ xa,
    const ushort* __restrict__ Btp, const ushort* __restrict__ Bta,
    const float* __restrict__ biasp, const float* __restrict__ biasa,
    const float* __restrict__ lns, const float* __restrict__ lnb,
    ushort* __restrict__ outp, ushort* __restrict__ outa, int pblk,
    const float* __restrict__ Wh, const float* __restrict__ bh,
    float* __restrict__ hout)
{
    __shared__ ushort As[4096];   // 8 KB, one K-step, 64 rows
    __shared__ ushort Bs[8192];   // 16 KB

    bool isp = (int)blockIdx.x < pblk;
    int  bid = isp ? blockIdx.x : (blockIdx.x - pblk);
    int  N   = isp ? NPAPER : NAUTH;
    int  K   = isp ? 384 : 256;
    const ushort* A0 = isp ? aggC : aggR;
    const ushort* A1 = isp ? aggW : xa;
    const ushort* A2 = isp ? xp   : xa;
    const ushort* Bt = isp ? Btp  : Bta;
    const float* bias = isp ? biasp : biasa;
    const float* lng  = lns + (isp ? 0 : 128);
    const float* lnbb = lnb + (isp ? 0 : 128);
    ushort* out = isp ? outp : outa;

    int t    = threadIdx.x;
    int w    = t >> 6;            // 0..3, wave owns rows w*16..w*16+15
    int lane = t & 63;
    int row0 = bid * 64;
    int l15  = lane & 15;
    int g4   = lane >> 4;

    f32x4 acc[8];
    #pragma unroll
    for (int f = 0; f < 8; f++) acc[f] = (f32x4){0.f, 0.f, 0.f, 0.f};

    int nstep = K >> 6;
    for (int st = 0; st < nstep; st++) {
        int kk  = st << 6;
        int seg = kk >> 7, kl = kk & 127;
        const ushort* Ap = (seg == 0) ? A0 : ((seg == 1) ? A1 : A2);

        #pragma unroll
        for (int p = 0; p < 2; p++) {
            int q  = p*256 + t;
            int ks = q >> 8, rb = (q >> 6) & 3, l = q & 63;
            int row = row0 + rb*16 + (l & 15);
            row = (row < N) ? row : (N - 1);
            int k = kl + ks*32 + (l >> 4)*8;
            int qbase = p*256 + w*64;
            GLD_LDS16(Ap + (size_t)row*DIM + k, As + qbase*8);
        }
        #pragma unroll
        for (int p = 0; p < 4; p++) {
            int q = p*256 + t;
            int qbase = p*256 + w*64;
            GLD_LDS16(Bt + ((size_t)st*8192 + (size_t)q*8), Bs + qbase*8);
        }
        __syncthreads();

        #pragma unroll
        for (int ks = 0; ks < 2; ks++) {
            short8 a0 = *(const short8*)(&As[((ks*4 + w)*64 + lane)*8]);
            #pragma unroll
            for (int f = 0; f < 8; f++) {
                short8 bv = *(const short8*)(&Bs[((ks*8 + f)*64 + lane)*8]);
                acc[f] = __builtin_amdgcn_mfma_f32_16x16x32_bf16(a0, bv, acc[f], 0, 0, 0);
            }
        }
        __syncthreads();
    }

    float* Whs = (float*)Bs;   // 128 x 20 floats = 10.25 KB <= 16 KB
    if (FUSE_HEAD) {
        for (int i = t; i < 2048; i += 256) {
            int r = i >> 4, c = i & 15;
            Whs[r*20 + c] = Wh[i];
        }
        __syncthreads();
    }

    float bv[8], gv[8], bbv[8];
    #pragma unroll
    for (int f = 0; f < 8; f++) {
        bv[f]  = bias[f*16 + l15];
        gv[f]  = lng [f*16 + l15];
        bbv[f] = lnbb[f*16 + l15];
    }
    #pragma unroll
    for (int i = 0; i < 4; i++) {
        int grow = row0 + w*16 + g4*4 + i;
        float vv[8];
        float s = 0.f, sq = 0.f;
        #pragma unroll
        for (int f = 0; f < 8; f++) {
            vv[f] = acc[f][i] + bv[f];
            s  += vv[f];
            sq += vv[f] * vv[f];
        }
        s += __shfl_xor(s, 1);  sq += __shfl_xor(sq, 1);
        s += __shfl_xor(s, 2);  sq += __shfl_xor(sq, 2);
        s += __shfl_xor(s, 4);  sq += __shfl_xor(sq, 4);
        s += __shfl_xor(s, 8);  sq += __shfl_xor(sq, 8);
        float m   = s * (1.f/128.f);
        float var = sq * (1.f/128.f) - m*m;
        float rr  = rsqrtf(var + 1e-5f);
        if (grow < N) {
            if (!FUSE_HEAD) {
                #pragma unroll
                for (int f = 0; f < 8; f++) {
                    float y = (vv[f] - m) * rr * gv[f] + bbv[f];
                    y = fmaxf(y, 0.f);
                    out[(size_t)grow*DIM + f*16 + l15] = f2b(y);
                }
            } else {
                float yr[8];
                #pragma unroll
                for (int f = 0; f < 8; f++) {
                    float y = (vv[f] - m) * rr * gv[f] + bbv[f];
                    y = fmaxf(y, 0.f);
                    yr[f] = b2f((uint)f2b(y));
                }
                f32x4 p0 = {0,0,0,0}, p1 = {0,0,0,0},
                      p2 = {0,0,0,0}, p3 = {0,0,0,0};
                #pragma unroll
                for (int f = 0; f < 8; f++) {
                    const float* wr = Whs + (f*16 + l15)*20;
                    p0 += yr[f] * *(const f32x4*)(wr + 0);
                    p1 += yr[f] * *(const f32x4*)(wr + 4);
                    p2 += yr[f] * *(const f32x4*)(wr + 8);
                    p3 += yr[f] * *(const f32x4*)(wr + 12);
                }
                #pragma unroll
                for (int mskk = 1; mskk <= 8; mskk <<= 1) {
                    #pragma unroll
                    for (int c = 0; c < 4; c++) {
                        p0[c] += __shfl_xor(p0[c], mskk);
                        p1[c] += __shfl_xor(p1[c], mskk);
                        p2[c] += __shfl_xor(p2[c], mskk);
                        p3[c] += __shfl_xor(p3[c], mskk);
                    }
                }
                if (l15 == 0) {
                    float* ho = hout + (size_t)grow * NCLS;
                    #pragma unroll
                    for (int c = 0; c < 4; c++) ho[c]      = p0[c] + bh[c];
                    #pragma unroll
                    for (int c = 0; c < 4; c++) ho[4 + c]  = p1[c] + bh[4 + c];
                    #pragma unroll
                    for (int c = 0; c < 4; c++) ho[8 + c]  = p2[c] + bh[8 + c];
                    #pragma unroll
                    for (int c = 0; c < 4; c++) ho[12 + c] = p3[c] + bh[12 + c];
                }
            }
        }
    }
}

// ---------------------------------------------------------------------------
extern "C" void kernel_launch(void* const* d_in, const int* in_sizes, int n_in,
                              void* d_out, int out_size, void* d_ws, size_t ws_size,
                              hipStream_t stream)
{
    const float* x_paper  = (const float*)d_in[0];
    const float* x_author = (const float*)d_in[1];
    const int*   ei_cites = (const int*)d_in[2];
    const int*   ei_writes= (const int*)d_in[3];
    const int*   ei_rev   = (const int*)d_in[4];
    const float* Wl       = (const float*)d_in[5];
    const float* Wr       = (const float*)d_in[6];
    const float* bl       = (const float*)d_in[7];
    const float* linp     = (const float*)d_in[8];
    const float* lina     = (const float*)d_in[9];
    const float* ln_s     = (const float*)d_in[10];
    const float* ln_b     = (const float*)d_in[11];
    const float* Wh       = (const float*)d_in[12];
    const float* bh       = (const float*)d_in[13];
    float* out = (float*)d_out;

    float* ws = (float*)d_ws;
    size_t off = 0;
    float* biasp2 = ws + off; off += 2*128;
    float* biasa2 = ws + off; off += 2*128;

    ushort* uws = (ushort*)(ws + off);
    size_t uoff = 0;
    ushort* xpb0 = uws + uoff; uoff += (size_t)NPAPER * DIM;
    ushort* xab0 = uws + uoff; uoff += (size_t)NAUTH  * DIM;
    ushort* xpb1 = uws + uoff; uoff += (size_t)NPAPER * DIM;
    ushort* xab1 = uws + uoff; uoff += (size_t)NAUTH  * DIM;
    ushort* aggC = uws + uoff; uoff += (size_t)NPAPER * DIM;
    ushort* aggW = uws + uoff; uoff += (size_t)NPAPER * DIM;
    ushort* aggR = uws + uoff; uoff += (size_t)NAUTH  * DIM;
    ushort* Btp  = uws + uoff; uoff += 2*49152;
    ushort* Bta  = uws + uoff; uoff += 2*32768;
    if (uoff & 3) uoff += 4 - (uoff & 3);   // 8B-align what follows

    uint2* stage = (uint2*)(uws + uoff);           // NB*BCAP uint2 = 24 MB
    uint2* rowse = stage + (size_t)NB*BCAP;        // NTOT uint2 = 2 MB
    int*   colAll = (int*)(rowse + NTOT);          // NB*BCAP int = 12 MB
    int*   cursor = colAll + (size_t)NB*BCAP;      // 256 ints

    // L0: zero bucket cursors
    hipMemsetAsync(cursor, 0, 256*4, stream);
    // L1: bucket emit (fixed-capacity buckets; depends only on edge lists)
    bucket_emit<<<NBLK_E, 256, 0, stream>>>(ei_cites, ei_writes, ei_rev,
                                            cursor, stage);
    // L2: fillB ∥ to_bf16 ∥ build_bt2 ∥ fold_bias2 (all lean)
    misc1<<<NB + TOBF + BTB + 2, 256, 0, stream>>>(
        stage, cursor, rowse, colAll,
        x_paper, x_author, xpb0, xab0,
        Wl, Wr, bl, linp, lina,
        Btp, Bta, biasp2, biasa2);

    // ---- layer 0 ----
    gather_seg<<<(size_t)NTOT*16/256, 256, 0, stream>>>(
        0, NTOT, xpb0, xab0, rowse, colAll, aggC, aggW, aggR);
    gemm_ln2<0><<<PBLK64 + ABLK64, 256, 0, stream>>>(
        aggC, aggW, aggR, xpb0, xab0,
        Btp, Bta, biasp2, biasa2, ln_s, ln_b,
        xpb1, xab1, PBLK64, nullptr, nullptr, nullptr);

    // ---- layer 1 (author path dead; head fused into paper GEMM epilogue) ----
    gather_seg<<<(size_t)2*NPAPER*16/256, 256, 0, stream>>>(
        0, 2*NPAPER, xpb1, xab1, rowse, colAll, aggC, aggW, aggR);
    gemm_ln2<1><<<PBLK64, 256, 0, stream>>>(
        aggC, aggW, aggR, xpb1, xab1,
        Btp + 49152, Bta + 32768, biasp2 + 128, biasa2 + 128,
        ln_s + 256, ln_b + 256,
        nullptr, nullptr, PBLK64, Wh, bh, out);
}